// Round 10
// baseline (420.099 us; speedup 1.0000x reference)
//
#include <hip/hip_runtime.h>
#include <hip/hip_bf16.h>

// VQDistortionLoss: fused cdist -> softmax -> soft-recon -> masked MSE.
// R9 = R8 + non-temporal streaming (single mechanism fix).
//   R8 post-mortem: balance worked, but blocks at unrelated kt phases broke
//   codebook L2 residency (bf16 codebook = 4MB = exactly one XCD L2); the z
//   stream (~100MB, zero reuse) evicted it -> FETCH 54->212MB, staging drains
//   stalled every barrier. Fix: nontemporal loads for z, nontemporal stores
//   for partial flush, nontemporal reads for merge partials. Staging keeps
//   default caching (wants L2 hits).
//   (R9 resubmission: nontemporal builtins need ext_vector/scalar pointers,
//    not HIP_vector_type -> f32x2n/u32x4n typedefs at the two failing sites.)

#define BB 8
#define DD 512
#define TT 4096
#define KKK 4096
#define ENC_STRIDE 320
#define KT 32
#define NKT (KKK / KT)     // 128
#define NW 8               // waves per block
#define ROWS 128           // rows per block
#define KBROW 2056         // ushorts per kb-row (2048 + 8 pad)
#define KBBYTES 4112
#define BUFB (8 * KBBYTES) // 32896 bytes per cs buffer

// ws layout
#define WS_C2    256
#define WS_RTS   16640
#define WS_CBH   32768
#define WS_PART  4227072ULL                    // u16 [512][128][512]
#define WS_ML    (WS_PART + 67108864ULL)       // f32 [512][128][2]
#define WS_NEED  (WS_ML + 524288ULL)           // ~71.9 MB

typedef __attribute__((ext_vector_type(8))) short bf16x8;  // 8 bf16 = 4 VGPR
typedef __attribute__((ext_vector_type(4))) float f32x4;
typedef __attribute__((ext_vector_type(2))) float f32x2n;  // nontemporal-safe
typedef __attribute__((ext_vector_type(4))) unsigned u32x4n;

union FragU { bf16x8 v; uint2 h2[2]; ushort us[8]; unsigned long long q[2]; uint4 u4; u32x4n un; };

static __device__ __forceinline__ ushort f2bf(float x) {   // RNE
  unsigned u = __float_as_uint(x);
  unsigned r = (u + 0x7FFFu + ((u >> 16) & 1u)) >> 16;
  return (ushort)r;
}
static __device__ __forceinline__ uint2 f4tobf(float4 v) {
  uint2 r;
  r.x = (unsigned)f2bf(v.x) | ((unsigned)f2bf(v.y) << 16);
  r.y = (unsigned)f2bf(v.z) | ((unsigned)f2bf(v.w) << 16);
  return r;
}
static __device__ __forceinline__ unsigned pk2bf(float lo, float hi) {
  return (__float_as_uint(lo) >> 16) | (__float_as_uint(hi) & 0xFFFF0000u);
}
static __device__ __forceinline__ float bfh2f(ushort h) {
  return __uint_as_float(((unsigned)h) << 16);
}
static __device__ __forceinline__ void gld_lds16(const void* g, void* l) {
  __builtin_amdgcn_global_load_lds(
      (const __attribute__((address_space(1))) unsigned*)g,
      (__attribute__((address_space(3))) unsigned*)l, 16, 0, 0);
}
static __device__ __forceinline__ unsigned lds_addr(const void* p) {
  return (unsigned)(size_t)(const __attribute__((address_space(3))) char*)p;
}

// ---- prep: c2[k] = |codebook[k]|^2 (f32), cbh = bf16 codebook -------------
__global__ __launch_bounds__(256) void vq_prep(const float* __restrict__ cb,
                                               float* __restrict__ c2,
                                               ushort* __restrict__ cbh) {
  int k = blockIdx.x * 4 + (threadIdx.x >> 6);
  int lane = threadIdx.x & 63;
  const float4* p = (const float4*)(cb + (size_t)k * DD + lane * 8);
  float4 a = p[0], b = p[1];
  if (cbh) {
    uint2 pa = f4tobf(a), pb = f4tobf(b);
    *(uint4*)(cbh + (size_t)k * DD + lane * 8) = make_uint4(pa.x, pa.y, pb.x, pb.y);
  }
  float s = a.x*a.x + a.y*a.y + a.z*a.z + a.w*a.w
          + b.x*b.x + b.y*b.y + b.z*b.z + b.w*b.w;
  #pragma unroll
  for (int m = 1; m <= 32; m <<= 1) s += __shfl_xor(s, m);
  if (lane == 0) c2[k] = s;
}

// ---- plan: compact active row-tiles, compute Q ----------------------------
__global__ void vq_plan(const int* __restrict__ lens, int* __restrict__ hdr,
                        int* __restrict__ rts) {
  int n = 0;
  for (int b2 = 0; b2 < BB; ++b2) {
    int v = (lens[b2] + (ENC_STRIDE - 1)) / ENC_STRIDE;
    v = v < TT ? v : TT;
    int tiles = (v + 127) >> 7;
    for (int t = 0; t < tiles; ++t) rts[n++] = (b2 << 5) | t;
  }
  hdr[0] = n;                       // nact
  hdr[1] = (n * 128 + 255) >> 8;    // Q = ceil(total/256)
  hdr[2] = n * 128;                 // total flat ktiles
}

// ---- split main: block c runs flat range [cQ,(c+1)Q), <=2 segments --------
__global__ __launch_bounds__(512, 2) void vq_main_ws(
    const float* __restrict__ sf,     // [B][D][T] f32
    const ushort* __restrict__ cbh,   // [K][D] bf16
    const float* __restrict__ c2,     // [K]
    const int* __restrict__ hdr,
    const int* __restrict__ rts,
    ushort* __restrict__ recon_p,     // [512][128][512] bf16 (normalized)
    float* __restrict__ ml) {         // [512][128][2] f32 {m, l}
  __shared__ __align__(128) ushort cs[4][8][KBROW];   // 131584 B
  __shared__ __align__(16) ushort wlds[2][NW][16][40];// 20480 B
  __shared__ float  alds[2][ROWS];
  __shared__ float  llds[ROWS];
  __shared__ int    flagv[128];

  const int Q = hdr[1], total = hdr[2];
  int start = blockIdx.x * Q;
  if (Q == 0 || start >= total) return;
  int end = start + Q;
  end = end < total ? end : total;
  int slot = blockIdx.x * 2;

  const int tid = threadIdx.x;
  const int w  = tid >> 6;
  const int l  = tid & 63;
  const int lg = l >> 4;
  const int ln = l & 15;
  const int sbase = (w * 4 + ((l >> 1) & 3)) * DD + (l >> 3) * 16 + (l & 1) * 8;
  const unsigned score_lane = (unsigned)((ln >> 2) * KBBYTES + (ln & 3) * 32
                                         + (lg >> 1) * 128 + (lg & 1) * 16);
  const unsigned tr_lane = (unsigned)(lg * KBBYTES + w * 512 + ln * 8);
  const unsigned cs0a = lds_addr(&cs[0][0][0]);

  while (start < end) {
    const int rt = start >> 7;
    const int k0 = start & 127;
    int seg_end = (rt + 1) << 7;
    seg_end = seg_end < end ? seg_end : end;
    const int klen = seg_end - start;
    const int rtv = rts[rt];
    const int b  = rtv >> 5;
    const int t0 = (rtv & 31) << 7;

    for (int i2 = tid; i2 < klen; i2 += 512) flagv[i2] = 0;

    // ---- za load (nontemporal: z has zero reuse; keep codebook in L2) ----
    const float* sfb = sf + (size_t)b * DD * TT;
    const int trow = t0 + w * 16 + ln;
    bf16x8 za[16];
    float z2 = 0.f;
    #pragma unroll
    for (int f = 0; f < 16; ++f) {
      #pragma unroll
      for (int j = 0; j < 8; ++j) {
        int d = f * 32 + lg * 8 + j;
        float v = __builtin_nontemporal_load(&sfb[(size_t)d * TT + trow]);
        z2 += v * v;
        za[f][j] = (short)f2bf(v);
      }
    }
    z2 += __shfl_xor(z2, 16);
    z2 += __shfl_xor(z2, 32);

    auto stage = [&](int kta, int buf) {
      const ushort* gb = cbh + (size_t)kta * KT * DD + sbase;
      ushort* lb = &cs[buf][w][0];
      #pragma unroll
      for (int q = 0; q < 4; ++q) gld_lds16(gb + q * 128, lb + q * 512);
    };

    stage(k0, 0);
    if (klen > 1) stage(k0 + 1, 1);
    if (klen > 2) stage(k0 + 2, 2);

    float mrow = -1e30f, lrow = 0.f;
    f32x4 acc[8][4];
    #pragma unroll
    for (int r = 0; r < 8; ++r)
      #pragma unroll
      for (int nt = 0; nt < 4; ++nt) acc[r][nt] = (f32x4){0.f, 0.f, 0.f, 0.f};

    f32x4 sc0, sc1;
    auto scores = [&](int sbuf) {
      const char* csb = (const char*)&cs[sbuf][0][0];
      sc0 = (f32x4){0,0,0,0}; sc1 = (f32x4){0,0,0,0};
      __builtin_amdgcn_s_setprio(1);
      #pragma unroll
      for (int f = 0; f < 16; ++f) {
        bf16x8 a0 = *(const bf16x8*)(csb + score_lane + f * 256);
        bf16x8 a1 = *(const bf16x8*)(csb + score_lane + 16448 + f * 256);
        sc0 = __builtin_amdgcn_mfma_f32_16x16x32_bf16(a0, za[f], sc0, 0, 0, 0);
        sc1 = __builtin_amdgcn_mfma_f32_16x16x32_bf16(a1, za[f], sc1, 0, 0, 0);
      }
      __builtin_amdgcn_s_setprio(0);
    };

    __syncthreads();               // flagv zero + stage(k0) drained
    scores(0);
    {  // softmax(local 0)
      const float4 c2a = *(const float4*)(c2 + k0 * KT + lg * 4);
      const float4 c2b = *(const float4*)(c2 + k0 * KT + 16 + lg * 4);
      float c2v[8] = {c2a.x, c2a.y, c2a.z, c2a.w, c2b.x, c2b.y, c2b.z, c2b.w};
      float sv[8];
      #pragma unroll
      for (int v = 0; v < 4; ++v) {
        sv[v]     = -sqrtf(fmaxf(z2 + c2v[v]     - 2.f * sc0[v], 1e-12f));
        sv[4 + v] = -sqrtf(fmaxf(z2 + c2v[4 + v] - 2.f * sc1[v], 1e-12f));
      }
      float lmax = sv[0];
      #pragma unroll
      for (int i = 1; i < 8; ++i) lmax = fmaxf(lmax, sv[i]);
      float tmax = fmaxf(lmax, __shfl_xor(lmax, 16));
      tmax = fmaxf(tmax, __shfl_xor(tmax, 32));
      float el[8], lsum = 0.f;
      #pragma unroll
      for (int i = 0; i < 8; ++i) { el[i] = __expf(sv[i] - lmax); lsum += el[i]; }
      mrow = tmax;
      float factor = __expf(lmax - tmax);
      float esum = lsum * factor;
      esum += __shfl_xor(esum, 16);
      esum += __shfl_xor(esum, 32);
      lrow = esum;
      uint4 pk;
      pk.x = pk2bf(el[0] * factor, el[1] * factor);
      pk.y = pk2bf(el[2] * factor, el[3] * factor);
      pk.z = pk2bf(el[4] * factor, el[5] * factor);
      pk.w = pk2bf(el[6] * factor, el[7] * factor);
      *(uint4*)&wlds[0][w][ln][lg * 8] = pk;
      if (lg == 0) alds[0][w * 16 + ln] = 1.f;
    }

    #pragma unroll 1
    for (int li = 1; li < klen; ++li) {
      __syncthreads();
      if (li + 2 < klen) stage(k0 + li + 2, (li + 2) & 3);

      scores(li & 3);

      const int kta = k0 + li;
      const float4 c2a = *(const float4*)(c2 + kta * KT + lg * 4);
      const float4 c2b = *(const float4*)(c2 + kta * KT + 16 + lg * 4);
      float c2v[8] = {c2a.x, c2a.y, c2a.z, c2a.w, c2b.x, c2b.y, c2b.z, c2b.w};
      float sv[8];
      #pragma unroll
      for (int v = 0; v < 4; ++v) {
        sv[v]     = -sqrtf(fmaxf(z2 + c2v[v]     - 2.f * sc0[v], 1e-12f));
        sv[4 + v] = -sqrtf(fmaxf(z2 + c2v[4 + v] - 2.f * sc1[v], 1e-12f));
      }
      float lmax = sv[0];
      #pragma unroll
      for (int i = 1; i < 8; ++i) lmax = fmaxf(lmax, sv[i]);
      float el[8], lsum = 0.f;
      #pragma unroll
      for (int i = 0; i < 8; ++i) { el[i] = __expf(sv[i] - lmax); lsum += el[i]; }

      const int lim1 = li - 1;
      const int s = lim1 & 1;
      const unsigned trb = cs0a + (unsigned)(lim1 & 3) * BUFB + tr_lane;
      unsigned long long tq0[4], tq1[4];
      #pragma unroll
      for (int nt = 0; nt < 4; ++nt) {
        asm volatile("ds_read_b64_tr_b16 %0, %2 offset:%3\n\t"
                     "ds_read_b64_tr_b16 %1, %2 offset:%4"
                     : "=&v"(tq0[nt]), "=&v"(tq1[nt])
                     : "v"(trb), "i"(nt * 128), "i"(16448 + nt * 128));
      }

      float tmax = fmaxf(lmax, __shfl_xor(lmax, 16));
      tmax = fmaxf(tmax, __shfl_xor(tmax, 32));
      const bool defer = (tmax <= mrow + 8.f);    // T13
      const float mnew = defer ? mrow : tmax;
      const float factor = __expf(lmax - mnew);   // <= e^8
      float esum = lsum * factor;
      esum += __shfl_xor(esum, 16);
      esum += __shfl_xor(esum, 32);
      const float alpha = defer ? 1.f : __expf(mrow - mnew);
      lrow = lrow * alpha + esum;
      mrow = mnew;
      uint4 pk;
      pk.x = pk2bf(el[0] * factor, el[1] * factor);
      pk.y = pk2bf(el[2] * factor, el[3] * factor);
      pk.z = pk2bf(el[4] * factor, el[5] * factor);
      pk.w = pk2bf(el[6] * factor, el[7] * factor);
      const int s2 = li & 1;
      *(uint4*)&wlds[s2][w][ln][lg * 8] = pk;
      if (lg == 0) alds[s2][w * 16 + ln] = alpha;
      if (!__all(defer) && l == 0) flagv[li] = 1;

      const int flg = flagv[lim1];
      asm volatile("s_waitcnt lgkmcnt(0)" ::: "memory");
      __builtin_amdgcn_sched_barrier(0);

      if (flg) {
        #pragma unroll
        for (int r = 0; r < 8; ++r)
          #pragma unroll
          for (int v = 0; v < 4; ++v) {
            float av = alds[s][r * 16 + lg * 4 + v];
            #pragma unroll
            for (int nt = 0; nt < 4; ++nt) acc[r][nt][v] *= av;
          }
      }
      FragU cf[4];
      #pragma unroll
      for (int nt = 0; nt < 4; ++nt) { cf[nt].q[0] = tq0[nt]; cf[nt].q[1] = tq1[nt]; }

      __builtin_amdgcn_s_setprio(1);
      #pragma unroll
      for (int rh = 0; rh < 2; ++rh) {
        bf16x8 wa4[4];
        #pragma unroll
        for (int r4 = 0; r4 < 4; ++r4)
          wa4[r4] = *(const bf16x8*)&wlds[s][rh * 4 + r4][ln][lg * 8];
        #pragma unroll
        for (int r4 = 0; r4 < 4; ++r4)
          #pragma unroll
          for (int nt = 0; nt < 4; ++nt)
            acc[rh * 4 + r4][nt] = __builtin_amdgcn_mfma_f32_16x16x32_bf16(
                wa4[r4], cf[nt].v, acc[rh * 4 + r4][nt], 0, 0, 0);
      }
      __builtin_amdgcn_s_setprio(0);
    }

    // ---- tail recon(klen-1) ----------------------------------------------
    __syncthreads();
    {
      const int lim1 = klen - 1;
      const int s = lim1 & 1;
      const unsigned trb = cs0a + (unsigned)(lim1 & 3) * BUFB + tr_lane;
      unsigned long long tq0[4], tq1[4];
      #pragma unroll
      for (int nt = 0; nt < 4; ++nt) {
        asm volatile("ds_read_b64_tr_b16 %0, %2 offset:%3\n\t"
                     "ds_read_b64_tr_b16 %1, %2 offset:%4"
                     : "=&v"(tq0[nt]), "=&v"(tq1[nt])
                     : "v"(trb), "i"(nt * 128), "i"(16448 + nt * 128));
      }
      const int flg = flagv[lim1];
      asm volatile("s_waitcnt lgkmcnt(0)" ::: "memory");
      __builtin_amdgcn_sched_barrier(0);
      if (flg) {
        #pragma unroll
        for (int r = 0; r < 8; ++r)
          #pragma unroll
          for (int v = 0; v < 4; ++v) {
            float av = alds[s][r * 16 + lg * 4 + v];
            #pragma unroll
            for (int nt = 0; nt < 4; ++nt) acc[r][nt][v] *= av;
          }
      }
      FragU cf[4];
      #pragma unroll
      for (int nt = 0; nt < 4; ++nt) { cf[nt].q[0] = tq0[nt]; cf[nt].q[1] = tq1[nt]; }
      #pragma unroll
      for (int rh = 0; rh < 2; ++rh) {
        bf16x8 wa4[4];
        #pragma unroll
        for (int r4 = 0; r4 < 4; ++r4)
          wa4[r4] = *(const bf16x8*)&wlds[s][rh * 4 + r4][ln][lg * 8];
        #pragma unroll
        for (int r4 = 0; r4 < 4; ++r4)
          #pragma unroll
          for (int nt = 0; nt < 4; ++nt)
            acc[rh * 4 + r4][nt] = __builtin_amdgcn_mfma_f32_16x16x32_bf16(
                wa4[r4], cf[nt].v, acc[rh * 4 + r4][nt], 0, 0, 0);
      }
    }

    // ---- flush partial: m,l + normalized recon (bf16, nontemporal) -------
    if (lg == 0) {
      llds[w * 16 + ln] = lrow;
      f32x2n mlv;
      mlv.x = mrow; mlv.y = lrow;
      __builtin_nontemporal_store(mlv, (f32x2n*)&ml[(size_t)(slot * 128 + w * 16 + ln) * 2]);
    }
    __syncthreads();
    {
      ushort* rp = recon_p + (size_t)slot * (128 * 512);
      #pragma unroll
      for (int r = 0; r < 8; ++r) {
        #pragma unroll
        for (int v = 0; v < 4; ++v) {
          const int row = r * 16 + lg * 4 + v;
          const float lv = llds[row];
          #pragma unroll
          for (int nt = 0; nt < 4; ++nt) {
            const int d = w * 64 + nt * 16 + ln;
            __builtin_nontemporal_store(f2bf(acc[r][nt][v] / lv),
                                        &rp[row * 512 + d]);
          }
        }
      }
    }
    __syncthreads();               // llds/flagv/cs reusable next segment

    start += klen;
    slot++;
  }
}

// ---- merge: flash-combine partials per row-tile + MSE + masked sum -------
__global__ __launch_bounds__(512) void vq_merge(
    const ushort* __restrict__ recon_p, const float* __restrict__ ml,
    const int* __restrict__ hdr, const int* __restrict__ rts,
    const int* __restrict__ lens, const float* __restrict__ cb,
    const int* __restrict__ codes, float* __restrict__ num) {
  __shared__ float red[128];
  const int i = blockIdx.x;
  const int nact = hdr[0];
  if (i >= nact) return;
  const int Q = hdr[1], total = hdr[2];
  const int rtv = rts[i];
  const int b = rtv >> 5;
  const int t0 = (rtv & 31) << 7;
  int vcount = (lens[b] + (ENC_STRIDE - 1)) / ENC_STRIDE;
  vcount = vcount < TT ? vcount : TT;

  const int tid = threadIdx.x;
  const int r = tid >> 2;
  const int q = tid & 3;
  const int flat0 = i << 7, flat1 = flat0 + 128;
  int c_lo = flat0 / Q;
  int c_hi = (flat1 - 1) / Q;
  c_hi = c_hi < 255 ? c_hi : 255;

  // pass 1: running max M over overlapping partials
  float M = -1e30f;
  for (int c = c_lo; c <= c_hi; ++c) {
    const int cs_ = c * Q;
    int ce = cs_ + Q; ce = ce < total ? ce : total;
    if (cs_ >= flat1 || ce <= flat0) continue;
    const int slot = c * 2 + (i - (cs_ >> 7));
    M = fmaxf(M, ml[(size_t)(slot * 128 + r) * 2]);
  }
  // pass 2: L
  float L = 0.f;
  for (int c = c_lo; c <= c_hi; ++c) {
    const int cs_ = c * Q;
    int ce = cs_ + Q; ce = ce < total ? ce : total;
    if (cs_ >= flat1 || ce <= flat0) continue;
    const int slot = c * 2 + (i - (cs_ >> 7));
    const float m_ = ml[(size_t)(slot * 128 + r) * 2];
    const float l_ = ml[(size_t)(slot * 128 + r) * 2 + 1];
    L += l_ * __expf(m_ - M);
  }
  const float invL = 1.f / L;

  const int tc = codes[b * TT + t0 + r];
  const float* targ = cb + (size_t)tc * DD + q * 128;

  float psum = 0.f;
  #pragma unroll 1
  for (int ch = 0; ch < 16; ++ch) {
    const int d0 = q * 128 + ch * 8;
    float rec[8] = {0.f, 0.f, 0.f, 0.f, 0.f, 0.f, 0.f, 0.f};
    for (int c = c_lo; c <= c_hi; ++c) {
      const int cs_ = c * Q;
      int ce = cs_ + Q; ce = ce < total ? ce : total;
      if (cs_ >= flat1 || ce <= flat0) continue;
      const int slot = c * 2 + (i - (cs_ >> 7));
      const float m_ = ml[(size_t)(slot * 128 + r) * 2];
      const float l_ = ml[(size_t)(slot * 128 + r) * 2 + 1];
      const float wn = l_ * __expf(m_ - M) * invL;
      const ushort* rp = recon_p + (size_t)slot * (128 * 512) + r * 512 + d0;
      FragU u;
      u.un = __builtin_nontemporal_load((const u32x4n*)rp);
      #pragma unroll
      for (int j = 0; j < 8; ++j) rec[j] += wn * bfh2f(u.us[j]);
    }
    const float4 tg0 = *(const float4*)(targ + ch * 8);
    const float4 tg1 = *(const float4*)(targ + ch * 8 + 4);
    float tg[8] = {tg0.x, tg0.y, tg0.z, tg0.w, tg1.x, tg1.y, tg1.z, tg1.w};
    #pragma unroll
    for (int j = 0; j < 8; ++j) { float df = rec[j] - tg[j]; psum += df * df; }
  }
  psum += __shfl_xor(psum, 1);
  psum += __shfl_xor(psum, 2);
  if (q == 0) red[r] = ((t0 + r) < vcount) ? psum * (1.f / DD) : 0.f;
  __syncthreads();
  if (tid < 128) {
    float val = red[tid];
    val += __shfl_xor(val, 1);
    val += __shfl_xor(val, 2);
    val += __shfl_xor(val, 4);
    val += __shfl_xor(val, 8);
    val += __shfl_xor(val, 16);
    val += __shfl_xor(val, 32);
    if ((tid & 63) == 0) atomicAdd(num, val);
  }
}

// ---- fallback main (R7, unchanged) ----------------------------------------
template <int GLD>
__global__ __launch_bounds__(512, 2) void vq_main(
    const float* __restrict__ sf, const float* __restrict__ cb,
    const ushort* __restrict__ cbh, const int* __restrict__ codes,
    const int* __restrict__ lens, const float* __restrict__ c2,
    float* __restrict__ num) {
  __shared__ __align__(128) ushort cs[4][8][KBROW];
  __shared__ __align__(16) ushort wlds[2][NW][16][40];
  __shared__ float  alds[2][ROWS];
  __shared__ float  llds[ROWS];
  __shared__ float  diffred[ROWS];
  __shared__ int    flagv[NKT];

  const int bid = blockIdx.x;
  const int b  = bid >> 5;
  const int t0 = (bid & 31) << 7;
  const int len = lens[b];
  int vcount = (len + (ENC_STRIDE - 1)) / ENC_STRIDE;
  vcount = vcount < TT ? vcount : TT;
  if (t0 >= vcount) return;

  const int tid = threadIdx.x;
  const int w  = tid >> 6;
  const int l  = tid & 63;
  const int lg = l >> 4;
  const int ln = l & 15;

  for (int i = tid; i < ROWS; i += 512) diffred[i] = 0.f;
  for (int i = tid; i < NKT; i += 512) flagv[i] = 0;

  const float* sfb = sf + (size_t)b * DD * TT;
  const int trow = t0 + w * 16 + ln;
  bf16x8 za[16];
  float z2 = 0.f;
  #pragma unroll
  for (int f = 0; f < 16; ++f) {
    #pragma unroll
    for (int j = 0; j < 8; ++j) {
      int d = f * 32 + lg * 8 + j;
      float v = __builtin_nontemporal_load(&sfb[(size_t)d * TT + trow]);
      z2 += v * v;
      za[f][j] = (short)f2bf(v);
    }
  }
  z2 += __shfl_xor(z2, 16);
  z2 += __shfl_xor(z2, 32);

  const int sbase = (w * 4 + ((l >> 1) & 3)) * DD + (l >> 3) * 16 + (l & 1) * 8;
  auto stage = [&](int kt, int buf) {
    if (GLD) {
      const ushort* gb = cbh + (size_t)kt * KT * DD + sbase;
      ushort* lb = &cs[buf][w][0];
      #pragma unroll
      for (int q = 0; q < 4; ++q) gld_lds16(gb + q * 128, lb + q * 512);
    } else {
      const float* gb = cb + (size_t)kt * KT * DD + sbase;
      #pragma unroll
      for (int q = 0; q < 4; ++q) {
        float4 v0 = *(const float4*)(gb + q * 128);
        float4 v1 = *(const float4*)(gb + q * 128 + 4);
        uint2 a0 = f4tobf(v0), a1 = f4tobf(v1);
        *(uint4*)&cs[buf][w][q * 512 + l * 8] = make_uint4(a0.x, a0.y, a1.x, a1.y);
      }
    }
  };

  stage(0, 0); stage(1, 1); stage(2, 2);

  float mrow = -1e30f, lrow = 0.f;
  f32x4 acc[8][4];
  #pragma unroll
  for (int r = 0; r < 8; ++r)
    #pragma unroll
    for (int nt = 0; nt < 4; ++nt) acc[r][nt] = (f32x4){0.f, 0.f, 0.f, 0.f};

  const unsigned score_lane = (unsigned)((ln >> 2) * KBBYTES + (ln & 3) * 32
                                         + (lg >> 1) * 128 + (lg & 1) * 16);
  const unsigned tr_lane = (unsigned)(lg * KBBYTES + w * 512 + ln * 8);
  const unsigned cs0a = lds_addr(&cs[0][0][0]);

  f32x4 sc0, sc1;
  auto scores = [&](int it, int sbuf) {
    const char* csb = (const char*)&cs[sbuf][0][0];
    sc0 = (f32x4){0,0,0,0}; sc1 = (f32x4){0,0,0,0};
    __builtin_amdgcn_s_setprio(1);
    #pragma unroll
    for (int f = 0; f < 16; ++f) {
      bf16x8 a0 = *(const bf16x8*)(csb + score_lane + f * 256);
      bf16x8 a1 = *(const bf16x8*)(csb + score_lane + 16448 + f * 256);
      sc0 = __builtin_amdgcn_mfma_f32_16x16x32_bf16(a0, za[f], sc0, 0, 0, 0);
      sc1 = __builtin_amdgcn_mfma_f32_16x16x32_bf16(a1, za[f], sc1, 0, 0, 0);
    }
    __builtin_amdgcn_s_setprio(0);
  };

  __syncthreads();
  scores(0, 0);
  {
    const float4 c2a = *(const float4*)(c2 + lg * 4);
    const float4 c2b = *(const float4*)(c2 + 16 + lg * 4);
    float c2v[8] = {c2a.x, c2a.y, c2a.z, c2a.w, c2b.x, c2b.y, c2b.z, c2b.w};
    float sv[8];
    #pragma unroll
    for (int v = 0; v < 4; ++v) {
      sv[v]     = -sqrtf(fmaxf(z2 + c2v[v]     - 2.f * sc0[v], 1e-12f));
      sv[4 + v] = -sqrtf(fmaxf(z2 + c2v[4 + v] - 2.f * sc1[v], 1e-12f));
    }
    float lmax = sv[0];
    #pragma unroll
    for (int i = 1; i < 8; ++i) lmax = fmaxf(lmax, sv[i]);
    float tmax = fmaxf(lmax, __shfl_xor(lmax, 16));
    tmax = fmaxf(tmax, __shfl_xor(tmax, 32));
    float el[8], lsum = 0.f;
    #pragma unroll
    for (int i = 0; i < 8; ++i) { el[i] = __expf(sv[i] - lmax); lsum += el[i]; }
    mrow = tmax;
    float factor = __expf(lmax - tmax);
    float esum = lsum * factor;
    esum += __shfl_xor(esum, 16);
    esum += __shfl_xor(esum, 32);
    lrow = esum;
    uint4 pk;
    pk.x = pk2bf(el[0] * factor, el[1] * factor);
    pk.y = pk2bf(el[2] * factor, el[3] * factor);
    pk.z = pk2bf(el[4] * factor, el[5] * factor);
    pk.w = pk2bf(el[6] * factor, el[7] * factor);
    *(uint4*)&wlds[0][w][ln][lg * 8] = pk;
    if (lg == 0) alds[0][w * 16 + ln] = 1.f;
  }

  #pragma unroll 1
  for (int it = 1; it < NKT; ++it) {
    __syncthreads();
    if (it + 2 < NKT) stage(it + 2, (it + 2) & 3);
    scores(it, it & 3);

    const float4 c2a = *(const float4*)(c2 + it * KT + lg * 4);
    const float4 c2b = *(const float4*)(c2 + it * KT + 16 + lg * 4);
    float c2v[8] = {c2a.x, c2a.y, c2a.z, c2a.w, c2b.x, c2b.y, c2b.z, c2b.w};
    float sv[8];
    #pragma unroll
    for (int v = 0; v < 4; ++v) {
      sv[v]     = -sqrtf(fmaxf(z2 + c2v[v]     - 2.f * sc0[v], 1e-12f));
      sv[4 + v] = -sqrtf(fmaxf(z2 + c2v[4 + v] - 2.f * sc1[v], 1e-12f));
    }
    float lmax = sv[0];
    #pragma unroll
    for (int i = 1; i < 8; ++i) lmax = fmaxf(lmax, sv[i]);
    float el[8], lsum = 0.f;
    #pragma unroll
    for (int i = 0; i < 8; ++i) { el[i] = __expf(sv[i] - lmax); lsum += el[i]; }

    const int itm1 = it - 1;
    const int s = itm1 & 1;
    const unsigned trb = cs0a + (unsigned)(itm1 & 3) * BUFB + tr_lane;
    unsigned long long tq0[4], tq1[4];
    #pragma unroll
    for (int nt = 0; nt < 4; ++nt) {
      asm volatile("ds_read_b64_tr_b16 %0, %2 offset:%3\n\t"
                   "ds_read_b64_tr_b16 %1, %2 offset:%4"
                   : "=&v"(tq0[nt]), "=&v"(tq1[nt])
                   : "v"(trb), "i"(nt * 128), "i"(16448 + nt * 128));
    }

    float tmax = fmaxf(lmax, __shfl_xor(lmax, 16));
    tmax = fmaxf(tmax, __shfl_xor(tmax, 32));
    const bool defer = (tmax <= mrow + 8.f);
    const float mnew = defer ? mrow : tmax;
    const float factor = __expf(lmax - mnew);
    float esum = lsum * factor;
    esum += __shfl_xor(esum, 16);
    esum += __shfl_xor(esum, 32);
    const float alpha = defer ? 1.f : __expf(mrow - mnew);
    lrow = lrow * alpha + esum;
    mrow = mnew;
    uint4 pk;
    pk.x = pk2bf(el[0] * factor, el[1] * factor);
    pk.y = pk2bf(el[2] * factor, el[3] * factor);
    pk.z = pk2bf(el[4] * factor, el[5] * factor);
    pk.w = pk2bf(el[6] * factor, el[7] * factor);
    const int s2 = it & 1;
    *(uint4*)&wlds[s2][w][ln][lg * 8] = pk;
    if (lg == 0) alds[s2][w * 16 + ln] = alpha;
    if (!__all(defer) && l == 0) flagv[it] = 1;

    const int flg = flagv[itm1];
    asm volatile("s_waitcnt lgkmcnt(0)" ::: "memory");
    __builtin_amdgcn_sched_barrier(0);

    if (flg) {
      #pragma unroll
      for (int r = 0; r < 8; ++r)
        #pragma unroll
        for (int v = 0; v < 4; ++v) {
          float av = alds[s][r * 16 + lg * 4 + v];
          #pragma unroll
          for (int nt = 0; nt < 4; ++nt) acc[r][nt][v] *= av;
        }
    }
    FragU cf[4];
    #pragma unroll
    for (int nt = 0; nt < 4; ++nt) { cf[nt].q[0] = tq0[nt]; cf[nt].q[1] = tq1[nt]; }

    __builtin_amdgcn_s_setprio(1);
    #pragma unroll
    for (int rh = 0; rh < 2; ++rh) {
      bf16x8 wa4[4];
      #pragma unroll
      for (int r4 = 0; r4 < 4; ++r4)
        wa4[r4] = *(const bf16x8*)&wlds[s][rh * 4 + r4][ln][lg * 8];
      #pragma unroll
      for (int r4 = 0; r4 < 4; ++r4)
        #pragma unroll
        for (int nt = 0; nt < 4; ++nt)
          acc[rh * 4 + r4][nt] = __builtin_amdgcn_mfma_f32_16x16x32_bf16(
              wa4[r4], cf[nt].v, acc[rh * 4 + r4][nt], 0, 0, 0);
    }
    __builtin_amdgcn_s_setprio(0);
  }

  __syncthreads();
  {
    const int itm1 = NKT - 1;
    const int s = itm1 & 1;
    const unsigned trb = cs0a + (unsigned)(itm1 & 3) * BUFB + tr_lane;
    unsigned long long tq0[4], tq1[4];
    #pragma unroll
    for (int nt = 0; nt < 4; ++nt) {
      asm volatile("ds_read_b64_tr_b16 %0, %2 offset:%3\n\t"
                   "ds_read_b64_tr_b16 %1, %2 offset:%4"
                   : "=&v"(tq0[nt]), "=&v"(tq1[nt])
                   : "v"(trb), "i"(nt * 128), "i"(16448 + nt * 128));
    }
    const int flg = flagv[itm1];
    asm volatile("s_waitcnt lgkmcnt(0)" ::: "memory");
    __builtin_amdgcn_sched_barrier(0);
    if (flg) {
      #pragma unroll
      for (int r = 0; r < 8; ++r)
        #pragma unroll
        for (int v = 0; v < 4; ++v) {
          float av = alds[s][r * 16 + lg * 4 + v];
          #pragma unroll
          for (int nt = 0; nt < 4; ++nt) acc[r][nt][v] *= av;
        }
    }
    FragU cf[4];
    #pragma unroll
    for (int nt = 0; nt < 4; ++nt) { cf[nt].q[0] = tq0[nt]; cf[nt].q[1] = tq1[nt]; }
    #pragma unroll
    for (int rh = 0; rh < 2; ++rh) {
      bf16x8 wa4[4];
      #pragma unroll
      for (int r4 = 0; r4 < 4; ++r4)
        wa4[r4] = *(const bf16x8*)&wlds[s][rh * 4 + r4][ln][lg * 8];
      #pragma unroll
      for (int r4 = 0; r4 < 4; ++r4)
        #pragma unroll
        for (int nt = 0; nt < 4; ++nt)
          acc[rh * 4 + r4][nt] = __builtin_amdgcn_mfma_f32_16x16x32_bf16(
              wa4[r4], cf[nt].v, acc[rh * 4 + r4][nt], 0, 0, 0);
    }
  }

  if (lg == 0) llds[w * 16 + ln] = lrow;
  __syncthreads();
  const int* tcodes = codes + b * TT + t0;
  #pragma unroll
  for (int r = 0; r < 8; ++r) {
    float pv[4];
    #pragma unroll
    for (int v = 0; v < 4; ++v) {
      const int row = r * 16 + lg * 4 + v;
      const float lv = llds[row];
      const int tc = tcodes[row];
      const float* erow = cb + (size_t)tc * DD + w * 64;
      float ps = 0.f;
      #pragma unroll
      for (int nt = 0; nt < 4; ++nt) {
        float rc = acc[r][nt][v] / lv;
        float df = rc - erow[nt * 16 + ln];
        ps += df * df;
      }
      pv[v] = ps;
    }
    #pragma unroll
    for (int v = 0; v < 4; ++v) {
      pv[v] += __shfl_xor(pv[v], 1);
      pv[v] += __shfl_xor(pv[v], 2);
      pv[v] += __shfl_xor(pv[v], 4);
      pv[v] += __shfl_xor(pv[v], 8);
    }
    if (ln == 0) {
      #pragma unroll
      for (int v = 0; v < 4; ++v)
        atomicAdd(&diffred[r * 16 + lg * 4 + v], pv[v]);
    }
  }
  __syncthreads();
  if (tid < ROWS) {
    float val = (t0 + tid < vcount) ? diffred[tid] * (1.f / DD) : 0.f;
    val += __shfl_xor(val, 1);
    val += __shfl_xor(val, 2);
    val += __shfl_xor(val, 4);
    val += __shfl_xor(val, 8);
    val += __shfl_xor(val, 16);
    val += __shfl_xor(val, 32);
    if ((tid & 63) == 0) atomicAdd(num, val);
  }
}

// ---- finalize: loss = num / (sum(mask) + 1e-8) ---------------------------
__global__ void vq_finalize(const float* __restrict__ num,
                            const int* __restrict__ lens,
                            float* __restrict__ out) {
  float denom = 0.f;
  for (int b = 0; b < BB; ++b) {
    int v = (lens[b] + (ENC_STRIDE - 1)) / ENC_STRIDE;
    v = v < TT ? v : TT;
    denom += (float)v;
  }
  out[0] = num[0] / (denom + 1e-8f);
}

extern "C" void kernel_launch(void* const* d_in, const int* in_sizes, int n_in,
                              void* d_out, int out_size, void* d_ws, size_t ws_size,
                              hipStream_t stream) {
  const float* sf    = (const float*)d_in[0];
  const float* cb    = (const float*)d_in[1];
  const int*   codes = (const int*)d_in[2];
  const int*   lens  = (const int*)d_in[3];
  float* out = (float*)d_out;
  float* num = (float*)d_ws;
  int*   hdr = (int*)((char*)d_ws + 16);
  float* c2  = (float*)((char*)d_ws + WS_C2);
  int*   rts = (int*)((char*)d_ws + WS_RTS);
  const size_t need_gld = WS_CBH + (size_t)KKK * DD * sizeof(ushort);
  ushort* cbh = (ws_size >= need_gld) ? (ushort*)((char*)d_ws + WS_CBH) : nullptr;

  (void)hipMemsetAsync(d_ws, 0, 4, stream);
  vq_prep<<<KKK / 4, 256, 0, stream>>>(cb, c2, cbh);

  if (cbh && ws_size >= WS_NEED) {
    ushort* recon_p = (ushort*)((char*)d_ws + WS_PART);
    float*  mlp     = (float*)((char*)d_ws + WS_ML);
    vq_plan<<<1, 1, 0, stream>>>(lens, hdr, rts);
    vq_main_ws<<<256, 512, 0, stream>>>(sf, cbh, c2, hdr, rts, recon_p, mlp);
    vq_merge<<<256, 512, 0, stream>>>(recon_p, mlp, hdr, rts, lens, cb, codes, num);
  } else {
    const int grid = (BB * TT) / ROWS;
    if (cbh)
      vq_main<1><<<grid, 512, 0, stream>>>(sf, cb, cbh, codes, lens, c2, num);
    else
      vq_main<0><<<grid, 512, 0, stream>>>(sf, cb, cbh, codes, lens, c2, num);
  }
  vq_finalize<<<1, 1, 0, stream>>>(num, lens, out);
}

// Round 11
// 390.294 us; speedup vs baseline: 1.0764x; 1.0764x over previous
//
#include <hip/hip_runtime.h>
#include <hip/hip_bf16.h>

// VQDistortionLoss: fused cdist -> softmax -> soft-recon -> masked MSE.
// R11 = R10 with two fixes:
//  (1) NT hints REVERTED on partial-flush stores and merge loads (R10 showed
//      they bypass L3 -> merge re-read 34MB from HBM, +35us). NT kept ONLY on
//      the za (z) stream loads.
//  (2) scores: 4 independent MFMA accumulate chains (even/odd k-steps) instead
//      of 2x16-deep dependent chains -> tests the latency-chain hypothesis
//      (main is ~50% pipe-idle; wall >> pipe demand).

#define BB 8
#define DD 512
#define TT 4096
#define KKK 4096
#define ENC_STRIDE 320
#define KT 32
#define NKT (KKK / KT)     // 128
#define NW 8               // waves per block
#define ROWS 128           // rows per block
#define KBROW 2056         // ushorts per kb-row (2048 + 8 pad)
#define KBBYTES 4112
#define BUFB (8 * KBBYTES) // 32896 bytes per cs buffer

// ws layout
#define WS_C2    256
#define WS_RTS   16640
#define WS_CBH   32768
#define WS_PART  4227072ULL                    // u16 [512][128][512]
#define WS_ML    (WS_PART + 67108864ULL)       // f32 [512][128][2]
#define WS_NEED  (WS_ML + 524288ULL)           // ~71.9 MB

typedef __attribute__((ext_vector_type(8))) short bf16x8;  // 8 bf16 = 4 VGPR
typedef __attribute__((ext_vector_type(4))) float f32x4;

union FragU { bf16x8 v; uint2 h2[2]; ushort us[8]; unsigned long long q[2]; uint4 u4; };

static __device__ __forceinline__ ushort f2bf(float x) {   // RNE
  unsigned u = __float_as_uint(x);
  unsigned r = (u + 0x7FFFu + ((u >> 16) & 1u)) >> 16;
  return (ushort)r;
}
static __device__ __forceinline__ uint2 f4tobf(float4 v) {
  uint2 r;
  r.x = (unsigned)f2bf(v.x) | ((unsigned)f2bf(v.y) << 16);
  r.y = (unsigned)f2bf(v.z) | ((unsigned)f2bf(v.w) << 16);
  return r;
}
static __device__ __forceinline__ unsigned pk2bf(float lo, float hi) {
  return (__float_as_uint(lo) >> 16) | (__float_as_uint(hi) & 0xFFFF0000u);
}
static __device__ __forceinline__ float bfh2f(ushort h) {
  return __uint_as_float(((unsigned)h) << 16);
}
static __device__ __forceinline__ void gld_lds16(const void* g, void* l) {
  __builtin_amdgcn_global_load_lds(
      (const __attribute__((address_space(1))) unsigned*)g,
      (__attribute__((address_space(3))) unsigned*)l, 16, 0, 0);
}
static __device__ __forceinline__ unsigned lds_addr(const void* p) {
  return (unsigned)(size_t)(const __attribute__((address_space(3))) char*)p;
}

// ---- prep: c2[k] = |codebook[k]|^2 (f32), cbh = bf16 codebook -------------
__global__ __launch_bounds__(256) void vq_prep(const float* __restrict__ cb,
                                               float* __restrict__ c2,
                                               ushort* __restrict__ cbh) {
  int k = blockIdx.x * 4 + (threadIdx.x >> 6);
  int lane = threadIdx.x & 63;
  const float4* p = (const float4*)(cb + (size_t)k * DD + lane * 8);
  float4 a = p[0], b = p[1];
  if (cbh) {
    uint2 pa = f4tobf(a), pb = f4tobf(b);
    *(uint4*)(cbh + (size_t)k * DD + lane * 8) = make_uint4(pa.x, pa.y, pb.x, pb.y);
  }
  float s = a.x*a.x + a.y*a.y + a.z*a.z + a.w*a.w
          + b.x*b.x + b.y*b.y + b.z*b.z + b.w*b.w;
  #pragma unroll
  for (int m = 1; m <= 32; m <<= 1) s += __shfl_xor(s, m);
  if (lane == 0) c2[k] = s;
}

// ---- plan: compact active row-tiles, compute Q ----------------------------
__global__ void vq_plan(const int* __restrict__ lens, int* __restrict__ hdr,
                        int* __restrict__ rts) {
  int n = 0;
  for (int b2 = 0; b2 < BB; ++b2) {
    int v = (lens[b2] + (ENC_STRIDE - 1)) / ENC_STRIDE;
    v = v < TT ? v : TT;
    int tiles = (v + 127) >> 7;
    for (int t = 0; t < tiles; ++t) rts[n++] = (b2 << 5) | t;
  }
  hdr[0] = n;                       // nact
  hdr[1] = (n * 128 + 255) >> 8;    // Q = ceil(total/256)
  hdr[2] = n * 128;                 // total flat ktiles
}

// ---- split main: block c runs flat range [cQ,(c+1)Q), <=2 segments --------
__global__ __launch_bounds__(512, 2) void vq_main_ws(
    const float* __restrict__ sf,     // [B][D][T] f32
    const ushort* __restrict__ cbh,   // [K][D] bf16
    const float* __restrict__ c2,     // [K]
    const int* __restrict__ hdr,
    const int* __restrict__ rts,
    ushort* __restrict__ recon_p,     // [512][128][512] bf16 (normalized)
    float* __restrict__ ml) {         // [512][128][2] f32 {m, l}
  __shared__ __align__(128) ushort cs[4][8][KBROW];   // 131584 B
  __shared__ __align__(16) ushort wlds[2][NW][16][40];// 20480 B
  __shared__ float  alds[2][ROWS];
  __shared__ float  llds[ROWS];
  __shared__ int    flagv[128];

  const int Q = hdr[1], total = hdr[2];
  int start = blockIdx.x * Q;
  if (Q == 0 || start >= total) return;
  int end = start + Q;
  end = end < total ? end : total;
  int slot = blockIdx.x * 2;

  const int tid = threadIdx.x;
  const int w  = tid >> 6;
  const int l  = tid & 63;
  const int lg = l >> 4;
  const int ln = l & 15;
  const int sbase = (w * 4 + ((l >> 1) & 3)) * DD + (l >> 3) * 16 + (l & 1) * 8;
  const unsigned score_lane = (unsigned)((ln >> 2) * KBBYTES + (ln & 3) * 32
                                         + (lg >> 1) * 128 + (lg & 1) * 16);
  const unsigned tr_lane = (unsigned)(lg * KBBYTES + w * 512 + ln * 8);
  const unsigned cs0a = lds_addr(&cs[0][0][0]);

  while (start < end) {
    const int rt = start >> 7;
    const int k0 = start & 127;
    int seg_end = (rt + 1) << 7;
    seg_end = seg_end < end ? seg_end : end;
    const int klen = seg_end - start;
    const int rtv = rts[rt];
    const int b  = rtv >> 5;
    const int t0 = (rtv & 31) << 7;

    for (int i2 = tid; i2 < klen; i2 += 512) flagv[i2] = 0;

    // ---- za load (nontemporal: z has zero reuse; keep codebook in L2) ----
    const float* sfb = sf + (size_t)b * DD * TT;
    const int trow = t0 + w * 16 + ln;
    bf16x8 za[16];
    float z2 = 0.f;
    #pragma unroll
    for (int f = 0; f < 16; ++f) {
      #pragma unroll
      for (int j = 0; j < 8; ++j) {
        int d = f * 32 + lg * 8 + j;
        float v = __builtin_nontemporal_load(&sfb[(size_t)d * TT + trow]);
        z2 += v * v;
        za[f][j] = (short)f2bf(v);
      }
    }
    z2 += __shfl_xor(z2, 16);
    z2 += __shfl_xor(z2, 32);

    auto stage = [&](int kta, int buf) {
      const ushort* gb = cbh + (size_t)kta * KT * DD + sbase;
      ushort* lb = &cs[buf][w][0];
      #pragma unroll
      for (int q = 0; q < 4; ++q) gld_lds16(gb + q * 128, lb + q * 512);
    };

    stage(k0, 0);
    if (klen > 1) stage(k0 + 1, 1);
    if (klen > 2) stage(k0 + 2, 2);

    float mrow = -1e30f, lrow = 0.f;
    f32x4 acc[8][4];
    #pragma unroll
    for (int r = 0; r < 8; ++r)
      #pragma unroll
      for (int nt = 0; nt < 4; ++nt) acc[r][nt] = (f32x4){0.f, 0.f, 0.f, 0.f};

    f32x4 sc0, sc1;
    // 4 independent accumulate chains (even/odd k-steps) -> chain depth 8
    auto scores = [&](int sbuf) {
      const char* csb = (const char*)&cs[sbuf][0][0];
      f32x4 e0s = (f32x4){0,0,0,0}, o0s = (f32x4){0,0,0,0};
      f32x4 e1s = (f32x4){0,0,0,0}, o1s = (f32x4){0,0,0,0};
      __builtin_amdgcn_s_setprio(1);
      #pragma unroll
      for (int f = 0; f < 8; ++f) {
        bf16x8 ae0 = *(const bf16x8*)(csb + score_lane + (2 * f) * 256);
        bf16x8 ao0 = *(const bf16x8*)(csb + score_lane + (2 * f + 1) * 256);
        bf16x8 ae1 = *(const bf16x8*)(csb + score_lane + 16448 + (2 * f) * 256);
        bf16x8 ao1 = *(const bf16x8*)(csb + score_lane + 16448 + (2 * f + 1) * 256);
        e0s = __builtin_amdgcn_mfma_f32_16x16x32_bf16(ae0, za[2 * f],     e0s, 0, 0, 0);
        o0s = __builtin_amdgcn_mfma_f32_16x16x32_bf16(ao0, za[2 * f + 1], o0s, 0, 0, 0);
        e1s = __builtin_amdgcn_mfma_f32_16x16x32_bf16(ae1, za[2 * f],     e1s, 0, 0, 0);
        o1s = __builtin_amdgcn_mfma_f32_16x16x32_bf16(ao1, za[2 * f + 1], o1s, 0, 0, 0);
      }
      __builtin_amdgcn_s_setprio(0);
      sc0 = e0s + o0s;
      sc1 = e1s + o1s;
    };

    __syncthreads();               // flagv zero + stage(k0) drained
    scores(0);
    {  // softmax(local 0)
      const float4 c2a = *(const float4*)(c2 + k0 * KT + lg * 4);
      const float4 c2b = *(const float4*)(c2 + k0 * KT + 16 + lg * 4);
      float c2v[8] = {c2a.x, c2a.y, c2a.z, c2a.w, c2b.x, c2b.y, c2b.z, c2b.w};
      float sv[8];
      #pragma unroll
      for (int v = 0; v < 4; ++v) {
        sv[v]     = -sqrtf(fmaxf(z2 + c2v[v]     - 2.f * sc0[v], 1e-12f));
        sv[4 + v] = -sqrtf(fmaxf(z2 + c2v[4 + v] - 2.f * sc1[v], 1e-12f));
      }
      float lmax = sv[0];
      #pragma unroll
      for (int i = 1; i < 8; ++i) lmax = fmaxf(lmax, sv[i]);
      float tmax = fmaxf(lmax, __shfl_xor(lmax, 16));
      tmax = fmaxf(tmax, __shfl_xor(tmax, 32));
      float el[8], lsum = 0.f;
      #pragma unroll
      for (int i = 0; i < 8; ++i) { el[i] = __expf(sv[i] - lmax); lsum += el[i]; }
      mrow = tmax;
      float factor = __expf(lmax - tmax);
      float esum = lsum * factor;
      esum += __shfl_xor(esum, 16);
      esum += __shfl_xor(esum, 32);
      lrow = esum;
      uint4 pk;
      pk.x = pk2bf(el[0] * factor, el[1] * factor);
      pk.y = pk2bf(el[2] * factor, el[3] * factor);
      pk.z = pk2bf(el[4] * factor, el[5] * factor);
      pk.w = pk2bf(el[6] * factor, el[7] * factor);
      *(uint4*)&wlds[0][w][ln][lg * 8] = pk;
      if (lg == 0) alds[0][w * 16 + ln] = 1.f;
    }

    #pragma unroll 1
    for (int li = 1; li < klen; ++li) {
      __syncthreads();
      if (li + 2 < klen) stage(k0 + li + 2, (li + 2) & 3);

      scores(li & 3);

      const int kta = k0 + li;
      const float4 c2a = *(const float4*)(c2 + kta * KT + lg * 4);
      const float4 c2b = *(const float4*)(c2 + kta * KT + 16 + lg * 4);
      float c2v[8] = {c2a.x, c2a.y, c2a.z, c2a.w, c2b.x, c2b.y, c2b.z, c2b.w};
      float sv[8];
      #pragma unroll
      for (int v = 0; v < 4; ++v) {
        sv[v]     = -sqrtf(fmaxf(z2 + c2v[v]     - 2.f * sc0[v], 1e-12f));
        sv[4 + v] = -sqrtf(fmaxf(z2 + c2v[4 + v] - 2.f * sc1[v], 1e-12f));
      }
      float lmax = sv[0];
      #pragma unroll
      for (int i = 1; i < 8; ++i) lmax = fmaxf(lmax, sv[i]);
      float el[8], lsum = 0.f;
      #pragma unroll
      for (int i = 0; i < 8; ++i) { el[i] = __expf(sv[i] - lmax); lsum += el[i]; }

      const int lim1 = li - 1;
      const int s = lim1 & 1;
      const unsigned trb = cs0a + (unsigned)(lim1 & 3) * BUFB + tr_lane;
      unsigned long long tq0[4], tq1[4];
      #pragma unroll
      for (int nt = 0; nt < 4; ++nt) {
        asm volatile("ds_read_b64_tr_b16 %0, %2 offset:%3\n\t"
                     "ds_read_b64_tr_b16 %1, %2 offset:%4"
                     : "=&v"(tq0[nt]), "=&v"(tq1[nt])
                     : "v"(trb), "i"(nt * 128), "i"(16448 + nt * 128));
      }

      float tmax = fmaxf(lmax, __shfl_xor(lmax, 16));
      tmax = fmaxf(tmax, __shfl_xor(tmax, 32));
      const bool defer = (tmax <= mrow + 8.f);    // T13
      const float mnew = defer ? mrow : tmax;
      const float factor = __expf(lmax - mnew);   // <= e^8
      float esum = lsum * factor;
      esum += __shfl_xor(esum, 16);
      esum += __shfl_xor(esum, 32);
      const float alpha = defer ? 1.f : __expf(mrow - mnew);
      lrow = lrow * alpha + esum;
      mrow = mnew;
      uint4 pk;
      pk.x = pk2bf(el[0] * factor, el[1] * factor);
      pk.y = pk2bf(el[2] * factor, el[3] * factor);
      pk.z = pk2bf(el[4] * factor, el[5] * factor);
      pk.w = pk2bf(el[6] * factor, el[7] * factor);
      const int s2 = li & 1;
      *(uint4*)&wlds[s2][w][ln][lg * 8] = pk;
      if (lg == 0) alds[s2][w * 16 + ln] = alpha;
      if (!__all(defer) && l == 0) flagv[li] = 1;

      const int flg = flagv[lim1];
      asm volatile("s_waitcnt lgkmcnt(0)" ::: "memory");
      __builtin_amdgcn_sched_barrier(0);

      if (flg) {
        #pragma unroll
        for (int r = 0; r < 8; ++r)
          #pragma unroll
          for (int v = 0; v < 4; ++v) {
            float av = alds[s][r * 16 + lg * 4 + v];
            #pragma unroll
            for (int nt = 0; nt < 4; ++nt) acc[r][nt][v] *= av;
          }
      }
      FragU cf[4];
      #pragma unroll
      for (int nt = 0; nt < 4; ++nt) { cf[nt].q[0] = tq0[nt]; cf[nt].q[1] = tq1[nt]; }

      __builtin_amdgcn_s_setprio(1);
      #pragma unroll
      for (int rh = 0; rh < 2; ++rh) {
        bf16x8 wa4[4];
        #pragma unroll
        for (int r4 = 0; r4 < 4; ++r4)
          wa4[r4] = *(const bf16x8*)&wlds[s][rh * 4 + r4][ln][lg * 8];
        #pragma unroll
        for (int r4 = 0; r4 < 4; ++r4)
          #pragma unroll
          for (int nt = 0; nt < 4; ++nt)
            acc[rh * 4 + r4][nt] = __builtin_amdgcn_mfma_f32_16x16x32_bf16(
                wa4[r4], cf[nt].v, acc[rh * 4 + r4][nt], 0, 0, 0);
      }
      __builtin_amdgcn_s_setprio(0);
    }

    // ---- tail recon(klen-1) ----------------------------------------------
    __syncthreads();
    {
      const int lim1 = klen - 1;
      const int s = lim1 & 1;
      const unsigned trb = cs0a + (unsigned)(lim1 & 3) * BUFB + tr_lane;
      unsigned long long tq0[4], tq1[4];
      #pragma unroll
      for (int nt = 0; nt < 4; ++nt) {
        asm volatile("ds_read_b64_tr_b16 %0, %2 offset:%3\n\t"
                     "ds_read_b64_tr_b16 %1, %2 offset:%4"
                     : "=&v"(tq0[nt]), "=&v"(tq1[nt])
                     : "v"(trb), "i"(nt * 128), "i"(16448 + nt * 128));
      }
      const int flg = flagv[lim1];
      asm volatile("s_waitcnt lgkmcnt(0)" ::: "memory");
      __builtin_amdgcn_sched_barrier(0);
      if (flg) {
        #pragma unroll
        for (int r = 0; r < 8; ++r)
          #pragma unroll
          for (int v = 0; v < 4; ++v) {
            float av = alds[s][r * 16 + lg * 4 + v];
            #pragma unroll
            for (int nt = 0; nt < 4; ++nt) acc[r][nt][v] *= av;
          }
      }
      FragU cf[4];
      #pragma unroll
      for (int nt = 0; nt < 4; ++nt) { cf[nt].q[0] = tq0[nt]; cf[nt].q[1] = tq1[nt]; }
      #pragma unroll
      for (int rh = 0; rh < 2; ++rh) {
        bf16x8 wa4[4];
        #pragma unroll
        for (int r4 = 0; r4 < 4; ++r4)
          wa4[r4] = *(const bf16x8*)&wlds[s][rh * 4 + r4][ln][lg * 8];
        #pragma unroll
        for (int r4 = 0; r4 < 4; ++r4)
          #pragma unroll
          for (int nt = 0; nt < 4; ++nt)
            acc[rh * 4 + r4][nt] = __builtin_amdgcn_mfma_f32_16x16x32_bf16(
                wa4[r4], cf[nt].v, acc[rh * 4 + r4][nt], 0, 0, 0);
      }
    }

    // ---- flush partial: m,l + normalized recon (plain stores -> L2/L3) ---
    if (lg == 0) {
      llds[w * 16 + ln] = lrow;
      float2 mlv; mlv.x = mrow; mlv.y = lrow;
      *(float2*)&ml[(size_t)(slot * 128 + w * 16 + ln) * 2] = mlv;
    }
    __syncthreads();
    {
      ushort* rp = recon_p + (size_t)slot * (128 * 512);
      #pragma unroll
      for (int r = 0; r < 8; ++r) {
        #pragma unroll
        for (int v = 0; v < 4; ++v) {
          const int row = r * 16 + lg * 4 + v;
          const float lv = llds[row];
          #pragma unroll
          for (int nt = 0; nt < 4; ++nt) {
            const int d = w * 64 + nt * 16 + ln;
            rp[row * 512 + d] = f2bf(acc[r][nt][v] / lv);
          }
        }
      }
    }
    __syncthreads();               // llds/flagv/cs reusable next segment

    start += klen;
    slot++;
  }
}

// ---- merge: flash-combine partials per row-tile + MSE + masked sum -------
__global__ __launch_bounds__(512) void vq_merge(
    const ushort* __restrict__ recon_p, const float* __restrict__ ml,
    const int* __restrict__ hdr, const int* __restrict__ rts,
    const int* __restrict__ lens, const float* __restrict__ cb,
    const int* __restrict__ codes, float* __restrict__ num) {
  __shared__ float red[128];
  const int i = blockIdx.x;
  const int nact = hdr[0];
  if (i >= nact) return;
  const int Q = hdr[1], total = hdr[2];
  const int rtv = rts[i];
  const int b = rtv >> 5;
  const int t0 = (rtv & 31) << 7;
  int vcount = (lens[b] + (ENC_STRIDE - 1)) / ENC_STRIDE;
  vcount = vcount < TT ? vcount : TT;

  const int tid = threadIdx.x;
  const int r = tid >> 2;
  const int q = tid & 3;
  const int flat0 = i << 7, flat1 = flat0 + 128;
  int c_lo = flat0 / Q;
  int c_hi = (flat1 - 1) / Q;
  c_hi = c_hi < 255 ? c_hi : 255;

  // pass 1: running max M over overlapping partials
  float M = -1e30f;
  for (int c = c_lo; c <= c_hi; ++c) {
    const int cs_ = c * Q;
    int ce = cs_ + Q; ce = ce < total ? ce : total;
    if (cs_ >= flat1 || ce <= flat0) continue;
    const int slot = c * 2 + (i - (cs_ >> 7));
    M = fmaxf(M, ml[(size_t)(slot * 128 + r) * 2]);
  }
  // pass 2: L
  float L = 0.f;
  for (int c = c_lo; c <= c_hi; ++c) {
    const int cs_ = c * Q;
    int ce = cs_ + Q; ce = ce < total ? ce : total;
    if (cs_ >= flat1 || ce <= flat0) continue;
    const int slot = c * 2 + (i - (cs_ >> 7));
    const float m_ = ml[(size_t)(slot * 128 + r) * 2];
    const float l_ = ml[(size_t)(slot * 128 + r) * 2 + 1];
    L += l_ * __expf(m_ - M);
  }
  const float invL = 1.f / L;

  const int tc = codes[b * TT + t0 + r];
  const float* targ = cb + (size_t)tc * DD + q * 128;

  float psum = 0.f;
  #pragma unroll 1
  for (int ch = 0; ch < 16; ++ch) {
    const int d0 = q * 128 + ch * 8;
    float rec[8] = {0.f, 0.f, 0.f, 0.f, 0.f, 0.f, 0.f, 0.f};
    for (int c = c_lo; c <= c_hi; ++c) {
      const int cs_ = c * Q;
      int ce = cs_ + Q; ce = ce < total ? ce : total;
      if (cs_ >= flat1 || ce <= flat0) continue;
      const int slot = c * 2 + (i - (cs_ >> 7));
      const float m_ = ml[(size_t)(slot * 128 + r) * 2];
      const float l_ = ml[(size_t)(slot * 128 + r) * 2 + 1];
      const float wn = l_ * __expf(m_ - M) * invL;
      const ushort* rp = recon_p + (size_t)slot * (128 * 512) + r * 512 + d0;
      FragU u; u.u4 = *(const uint4*)rp;
      #pragma unroll
      for (int j = 0; j < 8; ++j) rec[j] += wn * bfh2f(u.us[j]);
    }
    const float4 tg0 = *(const float4*)(targ + ch * 8);
    const float4 tg1 = *(const float4*)(targ + ch * 8 + 4);
    float tg[8] = {tg0.x, tg0.y, tg0.z, tg0.w, tg1.x, tg1.y, tg1.z, tg1.w};
    #pragma unroll
    for (int j = 0; j < 8; ++j) { float df = rec[j] - tg[j]; psum += df * df; }
  }
  psum += __shfl_xor(psum, 1);
  psum += __shfl_xor(psum, 2);
  if (q == 0) red[r] = ((t0 + r) < vcount) ? psum * (1.f / DD) : 0.f;
  __syncthreads();
  if (tid < 128) {
    float val = red[tid];
    val += __shfl_xor(val, 1);
    val += __shfl_xor(val, 2);
    val += __shfl_xor(val, 4);
    val += __shfl_xor(val, 8);
    val += __shfl_xor(val, 16);
    val += __shfl_xor(val, 32);
    if ((tid & 63) == 0) atomicAdd(num, val);
  }
}

// ---- fallback main (R7 structure, chain-split scores) ---------------------
template <int GLD>
__global__ __launch_bounds__(512, 2) void vq_main(
    const float* __restrict__ sf, const float* __restrict__ cb,
    const ushort* __restrict__ cbh, const int* __restrict__ codes,
    const int* __restrict__ lens, const float* __restrict__ c2,
    float* __restrict__ num) {
  __shared__ __align__(128) ushort cs[4][8][KBROW];
  __shared__ __align__(16) ushort wlds[2][NW][16][40];
  __shared__ float  alds[2][ROWS];
  __shared__ float  llds[ROWS];
  __shared__ float  diffred[ROWS];
  __shared__ int    flagv[NKT];

  const int bid = blockIdx.x;
  const int b  = bid >> 5;
  const int t0 = (bid & 31) << 7;
  const int len = lens[b];
  int vcount = (len + (ENC_STRIDE - 1)) / ENC_STRIDE;
  vcount = vcount < TT ? vcount : TT;
  if (t0 >= vcount) return;

  const int tid = threadIdx.x;
  const int w  = tid >> 6;
  const int l  = tid & 63;
  const int lg = l >> 4;
  const int ln = l & 15;

  for (int i = tid; i < ROWS; i += 512) diffred[i] = 0.f;
  for (int i = tid; i < NKT; i += 512) flagv[i] = 0;

  const float* sfb = sf + (size_t)b * DD * TT;
  const int trow = t0 + w * 16 + ln;
  bf16x8 za[16];
  float z2 = 0.f;
  #pragma unroll
  for (int f = 0; f < 16; ++f) {
    #pragma unroll
    for (int j = 0; j < 8; ++j) {
      int d = f * 32 + lg * 8 + j;
      float v = __builtin_nontemporal_load(&sfb[(size_t)d * TT + trow]);
      z2 += v * v;
      za[f][j] = (short)f2bf(v);
    }
  }
  z2 += __shfl_xor(z2, 16);
  z2 += __shfl_xor(z2, 32);

  const int sbase = (w * 4 + ((l >> 1) & 3)) * DD + (l >> 3) * 16 + (l & 1) * 8;
  auto stage = [&](int kt, int buf) {
    if (GLD) {
      const ushort* gb = cbh + (size_t)kt * KT * DD + sbase;
      ushort* lb = &cs[buf][w][0];
      #pragma unroll
      for (int q = 0; q < 4; ++q) gld_lds16(gb + q * 128, lb + q * 512);
    } else {
      const float* gb = cb + (size_t)kt * KT * DD + sbase;
      #pragma unroll
      for (int q = 0; q < 4; ++q) {
        float4 v0 = *(const float4*)(gb + q * 128);
        float4 v1 = *(const float4*)(gb + q * 128 + 4);
        uint2 a0 = f4tobf(v0), a1 = f4tobf(v1);
        *(uint4*)&cs[buf][w][q * 512 + l * 8] = make_uint4(a0.x, a0.y, a1.x, a1.y);
      }
    }
  };

  stage(0, 0); stage(1, 1); stage(2, 2);

  float mrow = -1e30f, lrow = 0.f;
  f32x4 acc[8][4];
  #pragma unroll
  for (int r = 0; r < 8; ++r)
    #pragma unroll
    for (int nt = 0; nt < 4; ++nt) acc[r][nt] = (f32x4){0.f, 0.f, 0.f, 0.f};

  const unsigned score_lane = (unsigned)((ln >> 2) * KBBYTES + (ln & 3) * 32
                                         + (lg >> 1) * 128 + (lg & 1) * 16);
  const unsigned tr_lane = (unsigned)(lg * KBBYTES + w * 512 + ln * 8);
  const unsigned cs0a = lds_addr(&cs[0][0][0]);

  f32x4 sc0, sc1;
  auto scores = [&](int sbuf) {
    const char* csb = (const char*)&cs[sbuf][0][0];
    f32x4 e0s = (f32x4){0,0,0,0}, o0s = (f32x4){0,0,0,0};
    f32x4 e1s = (f32x4){0,0,0,0}, o1s = (f32x4){0,0,0,0};
    __builtin_amdgcn_s_setprio(1);
    #pragma unroll
    for (int f = 0; f < 8; ++f) {
      bf16x8 ae0 = *(const bf16x8*)(csb + score_lane + (2 * f) * 256);
      bf16x8 ao0 = *(const bf16x8*)(csb + score_lane + (2 * f + 1) * 256);
      bf16x8 ae1 = *(const bf16x8*)(csb + score_lane + 16448 + (2 * f) * 256);
      bf16x8 ao1 = *(const bf16x8*)(csb + score_lane + 16448 + (2 * f + 1) * 256);
      e0s = __builtin_amdgcn_mfma_f32_16x16x32_bf16(ae0, za[2 * f],     e0s, 0, 0, 0);
      o0s = __builtin_amdgcn_mfma_f32_16x16x32_bf16(ao0, za[2 * f + 1], o0s, 0, 0, 0);
      e1s = __builtin_amdgcn_mfma_f32_16x16x32_bf16(ae1, za[2 * f],     e1s, 0, 0, 0);
      o1s = __builtin_amdgcn_mfma_f32_16x16x32_bf16(ao1, za[2 * f + 1], o1s, 0, 0, 0);
    }
    __builtin_amdgcn_s_setprio(0);
    sc0 = e0s + o0s;
    sc1 = e1s + o1s;
  };

  __syncthreads();
  scores(0);
  {
    const float4 c2a = *(const float4*)(c2 + lg * 4);
    const float4 c2b = *(const float4*)(c2 + 16 + lg * 4);
    float c2v[8] = {c2a.x, c2a.y, c2a.z, c2a.w, c2b.x, c2b.y, c2b.z, c2b.w};
    float sv[8];
    #pragma unroll
    for (int v = 0; v < 4; ++v) {
      sv[v]     = -sqrtf(fmaxf(z2 + c2v[v]     - 2.f * sc0[v], 1e-12f));
      sv[4 + v] = -sqrtf(fmaxf(z2 + c2v[4 + v] - 2.f * sc1[v], 1e-12f));
    }
    float lmax = sv[0];
    #pragma unroll
    for (int i = 1; i < 8; ++i) lmax = fmaxf(lmax, sv[i]);
    float tmax = fmaxf(lmax, __shfl_xor(lmax, 16));
    tmax = fmaxf(tmax, __shfl_xor(tmax, 32));
    float el[8], lsum = 0.f;
    #pragma unroll
    for (int i = 0; i < 8; ++i) { el[i] = __expf(sv[i] - lmax); lsum += el[i]; }
    mrow = tmax;
    float factor = __expf(lmax - tmax);
    float esum = lsum * factor;
    esum += __shfl_xor(esum, 16);
    esum += __shfl_xor(esum, 32);
    lrow = esum;
    uint4 pk;
    pk.x = pk2bf(el[0] * factor, el[1] * factor);
    pk.y = pk2bf(el[2] * factor, el[3] * factor);
    pk.z = pk2bf(el[4] * factor, el[5] * factor);
    pk.w = pk2bf(el[6] * factor, el[7] * factor);
    *(uint4*)&wlds[0][w][ln][lg * 8] = pk;
    if (lg == 0) alds[0][w * 16 + ln] = 1.f;
  }

  #pragma unroll 1
  for (int it = 1; it < NKT; ++it) {
    __syncthreads();
    if (it + 2 < NKT) stage(it + 2, (it + 2) & 3);
    scores(it & 3);

    const float4 c2a = *(const float4*)(c2 + it * KT + lg * 4);
    const float4 c2b = *(const float4*)(c2 + it * KT + 16 + lg * 4);
    float c2v[8] = {c2a.x, c2a.y, c2a.z, c2a.w, c2b.x, c2b.y, c2b.z, c2b.w};
    float sv[8];
    #pragma unroll
    for (int v = 0; v < 4; ++v) {
      sv[v]     = -sqrtf(fmaxf(z2 + c2v[v]     - 2.f * sc0[v], 1e-12f));
      sv[4 + v] = -sqrtf(fmaxf(z2 + c2v[4 + v] - 2.f * sc1[v], 1e-12f));
    }
    float lmax = sv[0];
    #pragma unroll
    for (int i = 1; i < 8; ++i) lmax = fmaxf(lmax, sv[i]);
    float el[8], lsum = 0.f;
    #pragma unroll
    for (int i = 0; i < 8; ++i) { el[i] = __expf(sv[i] - lmax); lsum += el[i]; }

    const int itm1 = it - 1;
    const int s = itm1 & 1;
    const unsigned trb = cs0a + (unsigned)(itm1 & 3) * BUFB + tr_lane;
    unsigned long long tq0[4], tq1[4];
    #pragma unroll
    for (int nt = 0; nt < 4; ++nt) {
      asm volatile("ds_read_b64_tr_b16 %0, %2 offset:%3\n\t"
                   "ds_read_b64_tr_b16 %1, %2 offset:%4"
                   : "=&v"(tq0[nt]), "=&v"(tq1[nt])
                   : "v"(trb), "i"(nt * 128), "i"(16448 + nt * 128));
    }

    float tmax = fmaxf(lmax, __shfl_xor(lmax, 16));
    tmax = fmaxf(tmax, __shfl_xor(tmax, 32));
    const bool defer = (tmax <= mrow + 8.f);
    const float mnew = defer ? mrow : tmax;
    const float factor = __expf(lmax - mnew);
    float esum = lsum * factor;
    esum += __shfl_xor(esum, 16);
    esum += __shfl_xor(esum, 32);
    const float alpha = defer ? 1.f : __expf(mrow - mnew);
    lrow = lrow * alpha + esum;
    mrow = mnew;
    uint4 pk;
    pk.x = pk2bf(el[0] * factor, el[1] * factor);
    pk.y = pk2bf(el[2] * factor, el[3] * factor);
    pk.z = pk2bf(el[4] * factor, el[5] * factor);
    pk.w = pk2bf(el[6] * factor, el[7] * factor);
    const int s2 = it & 1;
    *(uint4*)&wlds[s2][w][ln][lg * 8] = pk;
    if (lg == 0) alds[s2][w * 16 + ln] = alpha;
    if (!__all(defer) && l == 0) flagv[it] = 1;

    const int flg = flagv[itm1];
    asm volatile("s_waitcnt lgkmcnt(0)" ::: "memory");
    __builtin_amdgcn_sched_barrier(0);

    if (flg) {
      #pragma unroll
      for (int r = 0; r < 8; ++r)
        #pragma unroll
        for (int v = 0; v < 4; ++v) {
          float av = alds[s][r * 16 + lg * 4 + v];
          #pragma unroll
          for (int nt = 0; nt < 4; ++nt) acc[r][nt][v] *= av;
        }
    }
    FragU cf[4];
    #pragma unroll
    for (int nt = 0; nt < 4; ++nt) { cf[nt].q[0] = tq0[nt]; cf[nt].q[1] = tq1[nt]; }

    __builtin_amdgcn_s_setprio(1);
    #pragma unroll
    for (int rh = 0; rh < 2; ++rh) {
      bf16x8 wa4[4];
      #pragma unroll
      for (int r4 = 0; r4 < 4; ++r4)
        wa4[r4] = *(const bf16x8*)&wlds[s][rh * 4 + r4][ln][lg * 8];
      #pragma unroll
      for (int r4 = 0; r4 < 4; ++r4)
        #pragma unroll
        for (int nt = 0; nt < 4; ++nt)
          acc[rh * 4 + r4][nt] = __builtin_amdgcn_mfma_f32_16x16x32_bf16(
              wa4[r4], cf[nt].v, acc[rh * 4 + r4][nt], 0, 0, 0);
    }
    __builtin_amdgcn_s_setprio(0);
  }

  __syncthreads();
  {
    const int itm1 = NKT - 1;
    const int s = itm1 & 1;
    const unsigned trb = cs0a + (unsigned)(itm1 & 3) * BUFB + tr_lane;
    unsigned long long tq0[4], tq1[4];
    #pragma unroll
    for (int nt = 0; nt < 4; ++nt) {
      asm volatile("ds_read_b64_tr_b16 %0, %2 offset:%3\n\t"
                   "ds_read_b64_tr_b16 %1, %2 offset:%4"
                   : "=&v"(tq0[nt]), "=&v"(tq1[nt])
                   : "v"(trb), "i"(nt * 128), "i"(16448 + nt * 128));
    }
    const int flg = flagv[itm1];
    asm volatile("s_waitcnt lgkmcnt(0)" ::: "memory");
    __builtin_amdgcn_sched_barrier(0);
    if (flg) {
      #pragma unroll
      for (int r = 0; r < 8; ++r)
        #pragma unroll
        for (int v = 0; v < 4; ++v) {
          float av = alds[s][r * 16 + lg * 4 + v];
          #pragma unroll
          for (int nt = 0; nt < 4; ++nt) acc[r][nt][v] *= av;
        }
    }
    FragU cf[4];
    #pragma unroll
    for (int nt = 0; nt < 4; ++nt) { cf[nt].q[0] = tq0[nt]; cf[nt].q[1] = tq1[nt]; }
    #pragma unroll
    for (int rh = 0; rh < 2; ++rh) {
      bf16x8 wa4[4];
      #pragma unroll
      for (int r4 = 0; r4 < 4; ++r4)
        wa4[r4] = *(const bf16x8*)&wlds[s][rh * 4 + r4][ln][lg * 8];
      #pragma unroll
      for (int r4 = 0; r4 < 4; ++r4)
        #pragma unroll
        for (int nt = 0; nt < 4; ++nt)
          acc[rh * 4 + r4][nt] = __builtin_amdgcn_mfma_f32_16x16x32_bf16(
              wa4[r4], cf[nt].v, acc[rh * 4 + r4][nt], 0, 0, 0);
    }
  }

  if (lg == 0) llds[w * 16 + ln] = lrow;
  __syncthreads();
  const int* tcodes = codes + b * TT + t0;
  #pragma unroll
  for (int r = 0; r < 8; ++r) {
    float pv[4];
    #pragma unroll
    for (int v = 0; v < 4; ++v) {
      const int row = r * 16 + lg * 4 + v;
      const float lv = llds[row];
      const int tc = tcodes[row];
      const float* erow = cb + (size_t)tc * DD + w * 64;
      float ps = 0.f;
      #pragma unroll
      for (int nt = 0; nt < 4; ++nt) {
        float rc = acc[r][nt][v] / lv;
        float df = rc - erow[nt * 16 + ln];
        ps += df * df;
      }
      pv[v] = ps;
    }
    #pragma unroll
    for (int v = 0; v < 4; ++v) {
      pv[v] += __shfl_xor(pv[v], 1);
      pv[v] += __shfl_xor(pv[v], 2);
      pv[v] += __shfl_xor(pv[v], 4);
      pv[v] += __shfl_xor(pv[v], 8);
    }
    if (ln == 0) {
      #pragma unroll
      for (int v = 0; v < 4; ++v)
        atomicAdd(&diffred[r * 16 + lg * 4 + v], pv[v]);
    }
  }
  __syncthreads();
  if (tid < ROWS) {
    float val = (t0 + tid < vcount) ? diffred[tid] * (1.f / DD) : 0.f;
    val += __shfl_xor(val, 1);
    val += __shfl_xor(val, 2);
    val += __shfl_xor(val, 4);
    val += __shfl_xor(val, 8);
    val += __shfl_xor(val, 16);
    val += __shfl_xor(val, 32);
    if ((tid & 63) == 0) atomicAdd(num, val);
  }
}

// ---- finalize: loss = num / (sum(mask) + 1e-8) ---------------------------
__global__ void vq_finalize(const float* __restrict__ num,
                            const int* __restrict__ lens,
                            float* __restrict__ out) {
  float denom = 0.f;
  for (int b = 0; b < BB; ++b) {
    int v = (lens[b] + (ENC_STRIDE - 1)) / ENC_STRIDE;
    v = v < TT ? v : TT;
    denom += (float)v;
  }
  out[0] = num[0] / (denom + 1e-8f);
}

extern "C" void kernel_launch(void* const* d_in, const int* in_sizes, int n_in,
                              void* d_out, int out_size, void* d_ws, size_t ws_size,
                              hipStream_t stream) {
  const float* sf    = (const float*)d_in[0];
  const float* cb    = (const float*)d_in[1];
  const int*   codes = (const int*)d_in[2];
  const int*   lens  = (const int*)d_in[3];
  float* out = (float*)d_out;
  float* num = (float*)d_ws;
  int*   hdr = (int*)((char*)d_ws + 16);
  float* c2  = (float*)((char*)d_ws + WS_C2);
  int*   rts = (int*)((char*)d_ws + WS_RTS);
  const size_t need_gld = WS_CBH + (size_t)KKK * DD * sizeof(ushort);
  ushort* cbh = (ws_size >= need_gld) ? (ushort*)((char*)d_ws + WS_CBH) : nullptr;

  (void)hipMemsetAsync(d_ws, 0, 4, stream);
  vq_prep<<<KKK / 4, 256, 0, stream>>>(cb, c2, cbh);

  if (cbh && ws_size >= WS_NEED) {
    ushort* recon_p = (ushort*)((char*)d_ws + WS_PART);
    float*  mlp     = (float*)((char*)d_ws + WS_ML);
    vq_plan<<<1, 1, 0, stream>>>(lens, hdr, rts);
    vq_main_ws<<<256, 512, 0, stream>>>(sf, cbh, c2, hdr, rts, recon_p, mlp);
    vq_merge<<<256, 512, 0, stream>>>(recon_p, mlp, hdr, rts, lens, cb, codes, num);
  } else {
    const int grid = (BB * TT) / ROWS;
    if (cbh)
      vq_main<1><<<grid, 512, 0, stream>>>(sf, cb, cbh, codes, lens, c2, num);
    else
      vq_main<0><<<grid, 512, 0, stream>>>(sf, cb, cbh, codes, lens, c2, num);
  }
  vq_finalize<<<1, 1, 0, stream>>>(num, lens, out);
}

// Round 12
// 375.722 us; speedup vs baseline: 1.1181x; 1.0388x over previous
//
#include <hip/hip_runtime.h>
#include <hip/hip_bf16.h>

// VQDistortionLoss: fused cdist -> softmax -> soft-recon -> masked MSE.
// R12 = R11 + wave anti-phasing + fast sqrt + split merge.
//   R11 audit: MFMA 22% + VALU 34% + LDS ~40% ~= wall -> phases don't overlap;
//   occupancy reg-capped at 2 waves/SIMD; waves march phase-locked.
//   Fix: waves 0-3 run scores->softmax->recon (R11 order), waves 4-7 run
//   recon->scores->softmax. SIMD s hosts waves s and s+4 -> anti-phased pair
//   overlaps MFMA/LDS with VALU. All cross-wave deps (wlds/alds/flagv parity,
//   cs buffers) hold for both orders (recon(it-1) reads only pre-barrier state).
//   Riders: v_sqrt_f32 asm for score sqrts; merge split 2x (launch-bound).

#define BB 8
#define DD 512
#define TT 4096
#define KKK 4096
#define ENC_STRIDE 320
#define KT 32
#define NKT (KKK / KT)     // 128
#define NW 8               // waves per block
#define ROWS 128           // rows per block
#define KBROW 2056         // ushorts per kb-row (2048 + 8 pad)
#define KBBYTES 4112
#define BUFB (8 * KBBYTES) // 32896 bytes per cs buffer

// ws layout
#define WS_C2    256
#define WS_RTS   16640
#define WS_CBH   32768
#define WS_PART  4227072ULL                    // u16 [512][128][512]
#define WS_ML    (WS_PART + 67108864ULL)       // f32 [512][128][2]
#define WS_NEED  (WS_ML + 524288ULL)           // ~71.9 MB

typedef __attribute__((ext_vector_type(8))) short bf16x8;  // 8 bf16 = 4 VGPR
typedef __attribute__((ext_vector_type(4))) float f32x4;

union FragU { bf16x8 v; uint2 h2[2]; ushort us[8]; unsigned long long q[2]; uint4 u4; };

static __device__ __forceinline__ ushort f2bf(float x) {   // RNE
  unsigned u = __float_as_uint(x);
  unsigned r = (u + 0x7FFFu + ((u >> 16) & 1u)) >> 16;
  return (ushort)r;
}
static __device__ __forceinline__ uint2 f4tobf(float4 v) {
  uint2 r;
  r.x = (unsigned)f2bf(v.x) | ((unsigned)f2bf(v.y) << 16);
  r.y = (unsigned)f2bf(v.z) | ((unsigned)f2bf(v.w) << 16);
  return r;
}
static __device__ __forceinline__ unsigned pk2bf(float lo, float hi) {
  return (__float_as_uint(lo) >> 16) | (__float_as_uint(hi) & 0xFFFF0000u);
}
static __device__ __forceinline__ float bfh2f(ushort h) {
  return __uint_as_float(((unsigned)h) << 16);
}
static __device__ __forceinline__ float fsqrtf(float x) {  // v_sqrt_f32, ~1ulp
  float r; asm("v_sqrt_f32 %0, %1" : "=v"(r) : "v"(x)); return r;
}
static __device__ __forceinline__ void gld_lds16(const void* g, void* l) {
  __builtin_amdgcn_global_load_lds(
      (const __attribute__((address_space(1))) unsigned*)g,
      (__attribute__((address_space(3))) unsigned*)l, 16, 0, 0);
}
static __device__ __forceinline__ unsigned lds_addr(const void* p) {
  return (unsigned)(size_t)(const __attribute__((address_space(3))) char*)p;
}

// ---- prep: c2[k] = |codebook[k]|^2 (f32), cbh = bf16 codebook -------------
__global__ __launch_bounds__(256) void vq_prep(const float* __restrict__ cb,
                                               float* __restrict__ c2,
                                               ushort* __restrict__ cbh) {
  int k = blockIdx.x * 4 + (threadIdx.x >> 6);
  int lane = threadIdx.x & 63;
  const float4* p = (const float4*)(cb + (size_t)k * DD + lane * 8);
  float4 a = p[0], b = p[1];
  if (cbh) {
    uint2 pa = f4tobf(a), pb = f4tobf(b);
    *(uint4*)(cbh + (size_t)k * DD + lane * 8) = make_uint4(pa.x, pa.y, pb.x, pb.y);
  }
  float s = a.x*a.x + a.y*a.y + a.z*a.z + a.w*a.w
          + b.x*b.x + b.y*b.y + b.z*b.z + b.w*b.w;
  #pragma unroll
  for (int m = 1; m <= 32; m <<= 1) s += __shfl_xor(s, m);
  if (lane == 0) c2[k] = s;
}

// ---- plan: compact active row-tiles, compute Q ----------------------------
__global__ void vq_plan(const int* __restrict__ lens, int* __restrict__ hdr,
                        int* __restrict__ rts) {
  int n = 0;
  for (int b2 = 0; b2 < BB; ++b2) {
    int v = (lens[b2] + (ENC_STRIDE - 1)) / ENC_STRIDE;
    v = v < TT ? v : TT;
    int tiles = (v + 127) >> 7;
    for (int t = 0; t < tiles; ++t) rts[n++] = (b2 << 5) | t;
  }
  hdr[0] = n;                       // nact
  hdr[1] = (n * 128 + 255) >> 8;    // Q = ceil(total/256)
  hdr[2] = n * 128;                 // total flat ktiles
}

// ---- split main: block c runs flat range [cQ,(c+1)Q), <=2 segments --------
__global__ __launch_bounds__(512, 2) void vq_main_ws(
    const float* __restrict__ sf,     // [B][D][T] f32
    const ushort* __restrict__ cbh,   // [K][D] bf16
    const float* __restrict__ c2,     // [K]
    const int* __restrict__ hdr,
    const int* __restrict__ rts,
    ushort* __restrict__ recon_p,     // [512][128][512] bf16 (normalized)
    float* __restrict__ ml) {         // [512][128][2] f32 {m, l}
  __shared__ __align__(128) ushort cs[4][8][KBROW];   // 131584 B
  __shared__ __align__(16) ushort wlds[2][NW][16][40];// 20480 B
  __shared__ float  alds[2][ROWS];
  __shared__ float  llds[ROWS];
  __shared__ int    flagv[128];

  const int Q = hdr[1], total = hdr[2];
  int start = blockIdx.x * Q;
  if (Q == 0 || start >= total) return;
  int end = start + Q;
  end = end < total ? end : total;
  int slot = blockIdx.x * 2;

  const int tid = threadIdx.x;
  const int w  = tid >> 6;
  const int l  = tid & 63;
  const int lg = l >> 4;
  const int ln = l & 15;
  const int sbase = (w * 4 + ((l >> 1) & 3)) * DD + (l >> 3) * 16 + (l & 1) * 8;
  const unsigned score_lane = (unsigned)((ln >> 2) * KBBYTES + (ln & 3) * 32
                                         + (lg >> 1) * 128 + (lg & 1) * 16);
  const unsigned tr_lane = (unsigned)(lg * KBBYTES + w * 512 + ln * 8);
  const unsigned cs0a = lds_addr(&cs[0][0][0]);

  while (start < end) {
    const int rt = start >> 7;
    const int k0 = start & 127;
    int seg_end = (rt + 1) << 7;
    seg_end = seg_end < end ? seg_end : end;
    const int klen = seg_end - start;
    const int rtv = rts[rt];
    const int b  = rtv >> 5;
    const int t0 = (rtv & 31) << 7;

    for (int i2 = tid; i2 < klen; i2 += 512) flagv[i2] = 0;

    // ---- za load (nontemporal: z has zero reuse; keep codebook in L2) ----
    const float* sfb = sf + (size_t)b * DD * TT;
    const int trow = t0 + w * 16 + ln;
    bf16x8 za[16];
    float z2 = 0.f;
    #pragma unroll
    for (int f = 0; f < 16; ++f) {
      #pragma unroll
      for (int j = 0; j < 8; ++j) {
        int d = f * 32 + lg * 8 + j;
        float v = __builtin_nontemporal_load(&sfb[(size_t)d * TT + trow]);
        z2 += v * v;
        za[f][j] = (short)f2bf(v);
      }
    }
    z2 += __shfl_xor(z2, 16);
    z2 += __shfl_xor(z2, 32);

    auto stage = [&](int kta, int buf) {
      const ushort* gb = cbh + (size_t)kta * KT * DD + sbase;
      ushort* lb = &cs[buf][w][0];
      #pragma unroll
      for (int q = 0; q < 4; ++q) gld_lds16(gb + q * 128, lb + q * 512);
    };

    stage(k0, 0);
    if (klen > 1) stage(k0 + 1, 1);
    if (klen > 2) stage(k0 + 2, 2);

    float mrow = -1e30f, lrow = 0.f;
    f32x4 acc[8][4];
    #pragma unroll
    for (int r = 0; r < 8; ++r)
      #pragma unroll
      for (int nt = 0; nt < 4; ++nt) acc[r][nt] = (f32x4){0.f, 0.f, 0.f, 0.f};

    f32x4 sc0, sc1;
    // 4 independent accumulate chains (even/odd k-steps)
    auto scores = [&](int sbuf) {
      const char* csb = (const char*)&cs[sbuf][0][0];
      f32x4 e0s = (f32x4){0,0,0,0}, o0s = (f32x4){0,0,0,0};
      f32x4 e1s = (f32x4){0,0,0,0}, o1s = (f32x4){0,0,0,0};
      __builtin_amdgcn_s_setprio(1);
      #pragma unroll
      for (int f = 0; f < 8; ++f) {
        bf16x8 ae0 = *(const bf16x8*)(csb + score_lane + (2 * f) * 256);
        bf16x8 ao0 = *(const bf16x8*)(csb + score_lane + (2 * f + 1) * 256);
        bf16x8 ae1 = *(const bf16x8*)(csb + score_lane + 16448 + (2 * f) * 256);
        bf16x8 ao1 = *(const bf16x8*)(csb + score_lane + 16448 + (2 * f + 1) * 256);
        e0s = __builtin_amdgcn_mfma_f32_16x16x32_bf16(ae0, za[2 * f],     e0s, 0, 0, 0);
        o0s = __builtin_amdgcn_mfma_f32_16x16x32_bf16(ao0, za[2 * f + 1], o0s, 0, 0, 0);
        e1s = __builtin_amdgcn_mfma_f32_16x16x32_bf16(ae1, za[2 * f],     e1s, 0, 0, 0);
        o1s = __builtin_amdgcn_mfma_f32_16x16x32_bf16(ao1, za[2 * f + 1], o1s, 0, 0, 0);
      }
      __builtin_amdgcn_s_setprio(0);
      sc0 = e0s + o0s;
      sc1 = e1s + o1s;
    };

    // full softmax for tile kta (local index li): uses sc0/sc1
    auto softmax_full = [&](int kta, int li) {
      const float4 c2a = *(const float4*)(c2 + kta * KT + lg * 4);
      const float4 c2b = *(const float4*)(c2 + kta * KT + 16 + lg * 4);
      float c2v[8] = {c2a.x, c2a.y, c2a.z, c2a.w, c2b.x, c2b.y, c2b.z, c2b.w};
      float sv[8];
      #pragma unroll
      for (int v = 0; v < 4; ++v) {
        sv[v]     = -fsqrtf(fmaxf(z2 + c2v[v]     - 2.f * sc0[v], 1e-12f));
        sv[4 + v] = -fsqrtf(fmaxf(z2 + c2v[4 + v] - 2.f * sc1[v], 1e-12f));
      }
      float lmax = sv[0];
      #pragma unroll
      for (int i = 1; i < 8; ++i) lmax = fmaxf(lmax, sv[i]);
      float tmax = fmaxf(lmax, __shfl_xor(lmax, 16));
      tmax = fmaxf(tmax, __shfl_xor(tmax, 32));
      float el[8], lsum = 0.f;
      #pragma unroll
      for (int i = 0; i < 8; ++i) { el[i] = __expf(sv[i] - lmax); lsum += el[i]; }
      const bool defer = (li > 0) && (tmax <= mrow + 8.f);   // T13
      const float mnew = defer ? mrow : fmaxf(tmax, mrow);
      const float factor = __expf(lmax - mnew);
      float esum = lsum * factor;
      esum += __shfl_xor(esum, 16);
      esum += __shfl_xor(esum, 32);
      const float alpha = (li > 0 && !defer) ? __expf(mrow - mnew) : 1.f;
      lrow = lrow * alpha + esum;
      mrow = mnew;
      uint4 pk;
      pk.x = pk2bf(el[0] * factor, el[1] * factor);
      pk.y = pk2bf(el[2] * factor, el[3] * factor);
      pk.z = pk2bf(el[4] * factor, el[5] * factor);
      pk.w = pk2bf(el[6] * factor, el[7] * factor);
      *(uint4*)&wlds[li & 1][w][ln][lg * 8] = pk;
      if (lg == 0) alds[li & 1][w * 16 + ln] = alpha;
      if (li > 0 && !__all(defer) && l == 0) flagv[li] = 1;
    };

    // recon(lim1): tr reads + fence + rescale + MFMA cluster
    auto recon_full = [&](int lim1) {
      const int s = lim1 & 1;
      const unsigned trb = cs0a + (unsigned)(lim1 & 3) * BUFB + tr_lane;
      unsigned long long tq0[4], tq1[4];
      #pragma unroll
      for (int nt = 0; nt < 4; ++nt) {
        asm volatile("ds_read_b64_tr_b16 %0, %2 offset:%3\n\t"
                     "ds_read_b64_tr_b16 %1, %2 offset:%4"
                     : "=&v"(tq0[nt]), "=&v"(tq1[nt])
                     : "v"(trb), "i"(nt * 128), "i"(16448 + nt * 128));
      }
      const int flg = flagv[lim1];
      asm volatile("s_waitcnt lgkmcnt(0)" ::: "memory");
      __builtin_amdgcn_sched_barrier(0);
      if (flg) {
        #pragma unroll
        for (int r = 0; r < 8; ++r)
          #pragma unroll
          for (int v = 0; v < 4; ++v) {
            float av = alds[s][r * 16 + lg * 4 + v];
            #pragma unroll
            for (int nt = 0; nt < 4; ++nt) acc[r][nt][v] *= av;
          }
      }
      FragU cf[4];
      #pragma unroll
      for (int nt = 0; nt < 4; ++nt) { cf[nt].q[0] = tq0[nt]; cf[nt].q[1] = tq1[nt]; }
      __builtin_amdgcn_s_setprio(1);
      #pragma unroll
      for (int rh = 0; rh < 2; ++rh) {
        bf16x8 wa4[4];
        #pragma unroll
        for (int r4 = 0; r4 < 4; ++r4)
          wa4[r4] = *(const bf16x8*)&wlds[s][rh * 4 + r4][ln][lg * 8];
        #pragma unroll
        for (int r4 = 0; r4 < 4; ++r4)
          #pragma unroll
          for (int nt = 0; nt < 4; ++nt)
            acc[rh * 4 + r4][nt] = __builtin_amdgcn_mfma_f32_16x16x32_bf16(
                wa4[r4], cf[nt].v, acc[rh * 4 + r4][nt], 0, 0, 0);
      }
      __builtin_amdgcn_s_setprio(0);
    };

    __syncthreads();               // flagv zero + stage(k0) drained
    scores(0);
    softmax_full(k0, 0);

    // ---- anti-phased main loop: waves 0-3 S->SM->R, waves 4-7 R->S->SM ---
    if (w < 4) {
      #pragma unroll 1
      for (int li = 1; li < klen; ++li) {
        __syncthreads();
        if (li + 2 < klen) stage(k0 + li + 2, (li + 2) & 3);
        scores(li & 3);
        softmax_full(k0 + li, li);
        recon_full(li - 1);
      }
    } else {
      #pragma unroll 1
      for (int li = 1; li < klen; ++li) {
        __syncthreads();
        if (li + 2 < klen) stage(k0 + li + 2, (li + 2) & 3);
        recon_full(li - 1);
        scores(li & 3);
        softmax_full(k0 + li, li);
      }
    }

    // ---- tail recon(klen-1) ----------------------------------------------
    __syncthreads();
    recon_full(klen - 1);

    // ---- flush partial: m,l + normalized recon (bf16) --------------------
    if (lg == 0) {
      llds[w * 16 + ln] = lrow;
      float2 mlv; mlv.x = mrow; mlv.y = lrow;
      *(float2*)&ml[(size_t)(slot * 128 + w * 16 + ln) * 2] = mlv;
    }
    __syncthreads();
    {
      ushort* rp = recon_p + (size_t)slot * (128 * 512);
      #pragma unroll
      for (int r = 0; r < 8; ++r) {
        #pragma unroll
        for (int v = 0; v < 4; ++v) {
          const int row = r * 16 + lg * 4 + v;
          const float lv = llds[row];
          #pragma unroll
          for (int nt = 0; nt < 4; ++nt) {
            const int d = w * 64 + nt * 16 + ln;
            rp[row * 512 + d] = f2bf(acc[r][nt][v] / lv);
          }
        }
      }
    }
    __syncthreads();               // llds/flagv/cs reusable next segment

    start += klen;
    slot++;
  }
}

// ---- merge: flash-combine partials + MSE; grid (256, 2), 64 rows/block ----
__global__ __launch_bounds__(512) void vq_merge(
    const ushort* __restrict__ recon_p, const float* __restrict__ ml,
    const int* __restrict__ hdr, const int* __restrict__ rts,
    const int* __restrict__ lens, const float* __restrict__ cb,
    const int* __restrict__ codes, float* __restrict__ num) {
  __shared__ float red[64];
  const int i = blockIdx.x;
  const int nact = hdr[0];
  if (i >= nact) return;
  const int Q = hdr[1], total = hdr[2];
  const int rtv = rts[i];
  const int b = rtv >> 5;
  const int t0 = (rtv & 31) << 7;
  int vcount = (lens[b] + (ENC_STRIDE - 1)) / ENC_STRIDE;
  vcount = vcount < TT ? vcount : TT;

  const int tid = threadIdx.x;
  const int rl = tid >> 3;             // 0..63
  const int q  = tid & 7;              // 8 d-slices of 64
  const int r  = blockIdx.y * 64 + rl; // row within tile
  const int flat0 = i << 7, flat1 = flat0 + 128;
  int c_lo = flat0 / Q;
  int c_hi = (flat1 - 1) / Q;
  c_hi = c_hi < 255 ? c_hi : 255;

  // pass 1: running max M over overlapping partials
  float M = -1e30f;
  for (int c = c_lo; c <= c_hi; ++c) {
    const int cs_ = c * Q;
    int ce = cs_ + Q; ce = ce < total ? ce : total;
    if (cs_ >= flat1 || ce <= flat0) continue;
    const int slot = c * 2 + (i - (cs_ >> 7));
    M = fmaxf(M, ml[(size_t)(slot * 128 + r) * 2]);
  }
  // pass 2: L
  float L = 0.f;
  for (int c = c_lo; c <= c_hi; ++c) {
    const int cs_ = c * Q;
    int ce = cs_ + Q; ce = ce < total ? ce : total;
    if (cs_ >= flat1 || ce <= flat0) continue;
    const int slot = c * 2 + (i - (cs_ >> 7));
    const float m_ = ml[(size_t)(slot * 128 + r) * 2];
    const float l_ = ml[(size_t)(slot * 128 + r) * 2 + 1];
    L += l_ * __expf(m_ - M);
  }
  const float invL = 1.f / L;

  const int tc = codes[b * TT + t0 + r];
  const float* targ = cb + (size_t)tc * DD;

  float psum = 0.f;
  #pragma unroll 1
  for (int ch = 0; ch < 8; ++ch) {
    const int d0 = q * 64 + ch * 8;
    float rec[8] = {0.f, 0.f, 0.f, 0.f, 0.f, 0.f, 0.f, 0.f};
    for (int c = c_lo; c <= c_hi; ++c) {
      const int cs_ = c * Q;
      int ce = cs_ + Q; ce = ce < total ? ce : total;
      if (cs_ >= flat1 || ce <= flat0) continue;
      const int slot = c * 2 + (i - (cs_ >> 7));
      const float m_ = ml[(size_t)(slot * 128 + r) * 2];
      const float l_ = ml[(size_t)(slot * 128 + r) * 2 + 1];
      const float wn = l_ * __expf(m_ - M) * invL;
      const ushort* rp = recon_p + (size_t)slot * (128 * 512) + r * 512 + d0;
      FragU u; u.u4 = *(const uint4*)rp;
      #pragma unroll
      for (int j = 0; j < 8; ++j) rec[j] += wn * bfh2f(u.us[j]);
    }
    const float4 tg0 = *(const float4*)(targ + d0);
    const float4 tg1 = *(const float4*)(targ + d0 + 4);
    float tg[8] = {tg0.x, tg0.y, tg0.z, tg0.w, tg1.x, tg1.y, tg1.z, tg1.w};
    #pragma unroll
    for (int j = 0; j < 8; ++j) { float df = rec[j] - tg[j]; psum += df * df; }
  }
  psum += __shfl_xor(psum, 1);
  psum += __shfl_xor(psum, 2);
  psum += __shfl_xor(psum, 4);
  if (q == 0) red[rl] = ((t0 + r) < vcount) ? psum * (1.f / DD) : 0.f;
  __syncthreads();
  if (tid < 64) {
    float val = red[tid];
    val += __shfl_xor(val, 1);
    val += __shfl_xor(val, 2);
    val += __shfl_xor(val, 4);
    val += __shfl_xor(val, 8);
    val += __shfl_xor(val, 16);
    val += __shfl_xor(val, 32);
    if (tid == 0) atomicAdd(num, val);
  }
}

// ---- fallback main (R11, unused when ws is large enough) ------------------
template <int GLD>
__global__ __launch_bounds__(512, 2) void vq_main(
    const float* __restrict__ sf, const float* __restrict__ cb,
    const ushort* __restrict__ cbh, const int* __restrict__ codes,
    const int* __restrict__ lens, const float* __restrict__ c2,
    float* __restrict__ num) {
  __shared__ __align__(128) ushort cs[4][8][KBROW];
  __shared__ __align__(16) ushort wlds[2][NW][16][40];
  __shared__ float  alds[2][ROWS];
  __shared__ float  llds[ROWS];
  __shared__ float  diffred[ROWS];
  __shared__ int    flagv[NKT];

  const int bid = blockIdx.x;
  const int b  = bid >> 5;
  const int t0 = (bid & 31) << 7;
  const int len = lens[b];
  int vcount = (len + (ENC_STRIDE - 1)) / ENC_STRIDE;
  vcount = vcount < TT ? vcount : TT;
  if (t0 >= vcount) return;

  const int tid = threadIdx.x;
  const int w  = tid >> 6;
  const int l  = tid & 63;
  const int lg = l >> 4;
  const int ln = l & 15;

  for (int i = tid; i < ROWS; i += 512) diffred[i] = 0.f;
  for (int i = tid; i < NKT; i += 512) flagv[i] = 0;

  const float* sfb = sf + (size_t)b * DD * TT;
  const int trow = t0 + w * 16 + ln;
  bf16x8 za[16];
  float z2 = 0.f;
  #pragma unroll
  for (int f = 0; f < 16; ++f) {
    #pragma unroll
    for (int j = 0; j < 8; ++j) {
      int d = f * 32 + lg * 8 + j;
      float v = __builtin_nontemporal_load(&sfb[(size_t)d * TT + trow]);
      z2 += v * v;
      za[f][j] = (short)f2bf(v);
    }
  }
  z2 += __shfl_xor(z2, 16);
  z2 += __shfl_xor(z2, 32);

  const int sbase = (w * 4 + ((l >> 1) & 3)) * DD + (l >> 3) * 16 + (l & 1) * 8;
  auto stage = [&](int kt, int buf) {
    if (GLD) {
      const ushort* gb = cbh + (size_t)kt * KT * DD + sbase;
      ushort* lb = &cs[buf][w][0];
      #pragma unroll
      for (int q = 0; q < 4; ++q) gld_lds16(gb + q * 128, lb + q * 512);
    } else {
      const float* gb = cb + (size_t)kt * KT * DD + sbase;
      #pragma unroll
      for (int q = 0; q < 4; ++q) {
        float4 v0 = *(const float4*)(gb + q * 128);
        float4 v1 = *(const float4*)(gb + q * 128 + 4);
        uint2 a0 = f4tobf(v0), a1 = f4tobf(v1);
        *(uint4*)&cs[buf][w][q * 512 + l * 8] = make_uint4(a0.x, a0.y, a1.x, a1.y);
      }
    }
  };

  stage(0, 0); stage(1, 1); stage(2, 2);

  float mrow = -1e30f, lrow = 0.f;
  f32x4 acc[8][4];
  #pragma unroll
  for (int r = 0; r < 8; ++r)
    #pragma unroll
    for (int nt = 0; nt < 4; ++nt) acc[r][nt] = (f32x4){0.f, 0.f, 0.f, 0.f};

  const unsigned score_lane = (unsigned)((ln >> 2) * KBBYTES + (ln & 3) * 32
                                         + (lg >> 1) * 128 + (lg & 1) * 16);
  const unsigned tr_lane = (unsigned)(lg * KBBYTES + w * 512 + ln * 8);
  const unsigned cs0a = lds_addr(&cs[0][0][0]);

  f32x4 sc0, sc1;
  auto scores = [&](int sbuf) {
    const char* csb = (const char*)&cs[sbuf][0][0];
    f32x4 e0s = (f32x4){0,0,0,0}, o0s = (f32x4){0,0,0,0};
    f32x4 e1s = (f32x4){0,0,0,0}, o1s = (f32x4){0,0,0,0};
    __builtin_amdgcn_s_setprio(1);
    #pragma unroll
    for (int f = 0; f < 8; ++f) {
      bf16x8 ae0 = *(const bf16x8*)(csb + score_lane + (2 * f) * 256);
      bf16x8 ao0 = *(const bf16x8*)(csb + score_lane + (2 * f + 1) * 256);
      bf16x8 ae1 = *(const bf16x8*)(csb + score_lane + 16448 + (2 * f) * 256);
      bf16x8 ao1 = *(const bf16x8*)(csb + score_lane + 16448 + (2 * f + 1) * 256);
      e0s = __builtin_amdgcn_mfma_f32_16x16x32_bf16(ae0, za[2 * f],     e0s, 0, 0, 0);
      o0s = __builtin_amdgcn_mfma_f32_16x16x32_bf16(ao0, za[2 * f + 1], o0s, 0, 0, 0);
      e1s = __builtin_amdgcn_mfma_f32_16x16x32_bf16(ae1, za[2 * f],     e1s, 0, 0, 0);
      o1s = __builtin_amdgcn_mfma_f32_16x16x32_bf16(ao1, za[2 * f + 1], o1s, 0, 0, 0);
    }
    __builtin_amdgcn_s_setprio(0);
    sc0 = e0s + o0s;
    sc1 = e1s + o1s;
  };

  auto softmax_full = [&](int kta, int li) {
    const float4 c2a = *(const float4*)(c2 + kta * KT + lg * 4);
    const float4 c2b = *(const float4*)(c2 + kta * KT + 16 + lg * 4);
    float c2v[8] = {c2a.x, c2a.y, c2a.z, c2a.w, c2b.x, c2b.y, c2b.z, c2b.w};
    float sv[8];
    #pragma unroll
    for (int v = 0; v < 4; ++v) {
      sv[v]     = -fsqrtf(fmaxf(z2 + c2v[v]     - 2.f * sc0[v], 1e-12f));
      sv[4 + v] = -fsqrtf(fmaxf(z2 + c2v[4 + v] - 2.f * sc1[v], 1e-12f));
    }
    float lmax = sv[0];
    #pragma unroll
    for (int i = 1; i < 8; ++i) lmax = fmaxf(lmax, sv[i]);
    float tmax = fmaxf(lmax, __shfl_xor(lmax, 16));
    tmax = fmaxf(tmax, __shfl_xor(tmax, 32));
    float el[8], lsum = 0.f;
    #pragma unroll
    for (int i = 0; i < 8; ++i) { el[i] = __expf(sv[i] - lmax); lsum += el[i]; }
    const bool defer = (li > 0) && (tmax <= mrow + 8.f);
    const float mnew = defer ? mrow : fmaxf(tmax, mrow);
    const float factor = __expf(lmax - mnew);
    float esum = lsum * factor;
    esum += __shfl_xor(esum, 16);
    esum += __shfl_xor(esum, 32);
    const float alpha = (li > 0 && !defer) ? __expf(mrow - mnew) : 1.f;
    lrow = lrow * alpha + esum;
    mrow = mnew;
    uint4 pk;
    pk.x = pk2bf(el[0] * factor, el[1] * factor);
    pk.y = pk2bf(el[2] * factor, el[3] * factor);
    pk.z = pk2bf(el[4] * factor, el[5] * factor);
    pk.w = pk2bf(el[6] * factor, el[7] * factor);
    *(uint4*)&wlds[li & 1][w][ln][lg * 8] = pk;
    if (lg == 0) alds[li & 1][w * 16 + ln] = alpha;
    if (li > 0 && !__all(defer) && l == 0) flagv[li] = 1;
  };

  auto recon_full = [&](int lim1) {
    const int s = lim1 & 1;
    const unsigned trb = cs0a + (unsigned)(lim1 & 3) * BUFB + tr_lane;
    unsigned long long tq0[4], tq1[4];
    #pragma unroll
    for (int nt = 0; nt < 4; ++nt) {
      asm volatile("ds_read_b64_tr_b16 %0, %2 offset:%3\n\t"
                   "ds_read_b64_tr_b16 %1, %2 offset:%4"
                   : "=&v"(tq0[nt]), "=&v"(tq1[nt])
                   : "v"(trb), "i"(nt * 128), "i"(16448 + nt * 128));
    }
    const int flg = flagv[lim1];
    asm volatile("s_waitcnt lgkmcnt(0)" ::: "memory");
    __builtin_amdgcn_sched_barrier(0);
    if (flg) {
      #pragma unroll
      for (int r = 0; r < 8; ++r)
        #pragma unroll
        for (int v = 0; v < 4; ++v) {
          float av = alds[s][r * 16 + lg * 4 + v];
          #pragma unroll
          for (int nt = 0; nt < 4; ++nt) acc[r][nt][v] *= av;
        }
    }
    FragU cf[4];
    #pragma unroll
    for (int nt = 0; nt < 4; ++nt) { cf[nt].q[0] = tq0[nt]; cf[nt].q[1] = tq1[nt]; }
    __builtin_amdgcn_s_setprio(1);
    #pragma unroll
    for (int rh = 0; rh < 2; ++rh) {
      bf16x8 wa4[4];
      #pragma unroll
      for (int r4 = 0; r4 < 4; ++r4)
        wa4[r4] = *(const bf16x8*)&wlds[s][rh * 4 + r4][ln][lg * 8];
      #pragma unroll
      for (int r4 = 0; r4 < 4; ++r4)
        #pragma unroll
        for (int nt = 0; nt < 4; ++nt)
          acc[rh * 4 + r4][nt] = __builtin_amdgcn_mfma_f32_16x16x32_bf16(
              wa4[r4], cf[nt].v, acc[rh * 4 + r4][nt], 0, 0, 0);
    }
    __builtin_amdgcn_s_setprio(0);
  };

  __syncthreads();
  scores(0);
  softmax_full(0, 0);

  if (w < 4) {
    #pragma unroll 1
    for (int it = 1; it < NKT; ++it) {
      __syncthreads();
      if (it + 2 < NKT) stage(it + 2, (it + 2) & 3);
      scores(it & 3);
      softmax_full(it, it);
      recon_full(it - 1);
    }
  } else {
    #pragma unroll 1
    for (int it = 1; it < NKT; ++it) {
      __syncthreads();
      if (it + 2 < NKT) stage(it + 2, (it + 2) & 3);
      recon_full(it - 1);
      scores(it & 3);
      softmax_full(it, it);
    }
  }

  __syncthreads();
  recon_full(NKT - 1);

  if (lg == 0) llds[w * 16 + ln] = lrow;
  __syncthreads();
  const int* tcodes = codes + b * TT + t0;
  #pragma unroll
  for (int r = 0; r < 8; ++r) {
    float pv[4];
    #pragma unroll
    for (int v = 0; v < 4; ++v) {
      const int row = r * 16 + lg * 4 + v;
      const float lv = llds[row];
      const int tc = tcodes[row];
      const float* erow = cb + (size_t)tc * DD + w * 64;
      float ps = 0.f;
      #pragma unroll
      for (int nt = 0; nt < 4; ++nt) {
        float rc = acc[r][nt][v] / lv;
        float df = rc - erow[nt * 16 + ln];
        ps += df * df;
      }
      pv[v] = ps;
    }
    #pragma unroll
    for (int v = 0; v < 4; ++v) {
      pv[v] += __shfl_xor(pv[v], 1);
      pv[v] += __shfl_xor(pv[v], 2);
      pv[v] += __shfl_xor(pv[v], 4);
      pv[v] += __shfl_xor(pv[v], 8);
    }
    if (ln == 0) {
      #pragma unroll
      for (int v = 0; v < 4; ++v)
        atomicAdd(&diffred[r * 16 + lg * 4 + v], pv[v]);
    }
  }
  __syncthreads();
  if (tid < ROWS) {
    float val = (t0 + tid < vcount) ? diffred[tid] * (1.f / DD) : 0.f;
    val += __shfl_xor(val, 1);
    val += __shfl_xor(val, 2);
    val += __shfl_xor(val, 4);
    val += __shfl_xor(val, 8);
    val += __shfl_xor(val, 16);
    val += __shfl_xor(val, 32);
    if ((tid & 63) == 0) atomicAdd(num, val);
  }
}

// ---- finalize: loss = num / (sum(mask) + 1e-8) ---------------------------
__global__ void vq_finalize(const float* __restrict__ num,
                            const int* __restrict__ lens,
                            float* __restrict__ out) {
  float denom = 0.f;
  for (int b = 0; b < BB; ++b) {
    int v = (lens[b] + (ENC_STRIDE - 1)) / ENC_STRIDE;
    v = v < TT ? v : TT;
    denom += (float)v;
  }
  out[0] = num[0] / (denom + 1e-8f);
}

extern "C" void kernel_launch(void* const* d_in, const int* in_sizes, int n_in,
                              void* d_out, int out_size, void* d_ws, size_t ws_size,
                              hipStream_t stream) {
  const float* sf    = (const float*)d_in[0];
  const float* cb    = (const float*)d_in[1];
  const int*   codes = (const int*)d_in[2];
  const int*   lens  = (const int*)d_in[3];
  float* out = (float*)d_out;
  float* num = (float*)d_ws;
  int*   hdr = (int*)((char*)d_ws + 16);
  float* c2  = (float*)((char*)d_ws + WS_C2);
  int*   rts = (int*)((char*)d_ws + WS_RTS);
  const size_t need_gld = WS_CBH + (size_t)KKK * DD * sizeof(ushort);
  ushort* cbh = (ws_size >= need_gld) ? (ushort*)((char*)d_ws + WS_CBH) : nullptr;

  (void)hipMemsetAsync(d_ws, 0, 4, stream);
  vq_prep<<<KKK / 4, 256, 0, stream>>>(cb, c2, cbh);

  if (cbh && ws_size >= WS_NEED) {
    ushort* recon_p = (ushort*)((char*)d_ws + WS_PART);
    float*  mlp     = (float*)((char*)d_ws + WS_ML);
    vq_plan<<<1, 1, 0, stream>>>(lens, hdr, rts);
    vq_main_ws<<<256, 512, 0, stream>>>(sf, cbh, c2, hdr, rts, recon_p, mlp);
    vq_merge<<<dim3(256, 2), 512, 0, stream>>>(recon_p, mlp, hdr, rts, lens, cb, codes, num);
  } else {
    const int grid = (BB * TT) / ROWS;
    if (cbh)
      vq_main<1><<<grid, 512, 0, stream>>>(sf, cb, cbh, codes, lens, c2, num);
    else
      vq_main<0><<<grid, 512, 0, stream>>>(sf, cb, cbh, codes, lens, c2, num);
  }
  vq_finalize<<<1, 1, 0, stream>>>(num, lens, out);
}